// Round 14
// baseline (217.569 us; speedup 1.0000x reference)
//
#include <hip/hip_runtime.h>
#include <stdint.h>

// Problem constants (fixed by reference)
#define B_  8
#define C_  384
#define N_  1600
#define R_  4
#define S_  160
#define HW_ 40

typedef float  f32x4  __attribute__((ext_vector_type(4)));
typedef __bf16 bf16x8 __attribute__((ext_vector_type(8)));
typedef long long i64t;

__device__ __forceinline__ unsigned short f2bf(float x){
  __bf16 h = (__bf16)x;                         // RNE
  return __builtin_bit_cast(unsigned short, h);
}
__device__ __forceinline__ float bf2f(unsigned short u){
  return __builtin_bit_cast(float, (uint32_t)u << 16);
}
// pack 4 floats -> 4 OCP e4m3 bytes (v_cvt_pk_fp8_f32 on gfx950 emits OCP)
__device__ __forceinline__ uint32_t pk_fp8x4(float a, float b, float c, float d){
  int lo = __builtin_amdgcn_cvt_pk_fp8_f32(a, b, 0, false);
  int hi = __builtin_amdgcn_cvt_pk_fp8_f32(c, d, 0, false);
  return (uint32_t)(lo & 0xffff) | ((uint32_t)hi << 16);
}

// async global->LDS, 16B per lane; LDS dest is wave-uniform base + lane*16
__device__ __forceinline__ void gload_lds16(const void* g, void* l){
  __builtin_amdgcn_global_load_lds(
      (const __attribute__((address_space(1))) uint32_t*)g,
      (__attribute__((address_space(3))) uint32_t*)l, 16, 0, 0);
}

// ------------------------------------------- fused norm + transpose/convert ----
// One block per (nt, mat): reads the 64n x 384c f32 tile ONCE, writes V bf16
// inline, computes row norms from registers+LDS partials, then emits
// Q/K fp8 [n][c] from the bf16 LDS tile.
__global__ void prep_kernel(const float* __restrict__ feats,
                            const float* __restrict__ refs,
                            unsigned char* __restrict__ Qb,
                            unsigned char* __restrict__ Kb,
                            unsigned short* __restrict__ Vb){
  int nt = blockIdx.x, mat = blockIdx.y;
  __shared__ unsigned short tile[64][386];   // [n][c] bf16; 772B rows (odd dwords)
  __shared__ float ssp[64][17];              // per-n partial sums (16 producers)
  __shared__ float inv_sh[64];
  int t = threadIdx.x;
  bool isref = (mat >= B_);
  const float* src = isref ? refs  + (size_t)(mat - B_) * C_ * N_
                           : feats + (size_t)mat * C_ * N_;
  int n4  = t & 15;        // owns n = n4*4 .. +3 (fixed per thread)
  int crb = t >> 4;        // c-row base 0..15
  float ss4[4] = {0.f, 0.f, 0.f, 0.f};
#pragma unroll
  for (int ct = 0; ct < 6; ++ct){
#pragma unroll
    for (int i = 0; i < 4; ++i){
      int c = ct * 64 + crb + 16 * i;
      size_t off = (size_t)c * N_ + nt * 64 + n4 * 4;
      float4 v = *(const float4*)(src + off);
      ushort4 o;
      o.x = f2bf(v.x); o.y = f2bf(v.y); o.z = f2bf(v.z); o.w = f2bf(v.w);
      if (isref){
        unsigned short* vdst = Vb + (size_t)(mat - B_) * C_ * N_;
        *(ushort4*)(vdst + off) = o;       // V = raw bf16, same [c][n] layout
      }
      tile[n4*4+0][c] = o.x;
      tile[n4*4+1][c] = o.y;
      tile[n4*4+2][c] = o.z;
      tile[n4*4+3][c] = o.w;
      ss4[0] += v.x * v.x;  ss4[1] += v.y * v.y;
      ss4[2] += v.z * v.z;  ss4[3] += v.w * v.w;
    }
  }
#pragma unroll
  for (int j = 0; j < 4; ++j) ssp[n4*4+j][crb] = ss4[j];
  __syncthreads();
  if (t < 64){
    float s = 0.f;
#pragma unroll
    for (int p = 0; p < 16; ++p) s += ssp[t][p];
    inv_sh[t] = 1.f / fmaxf(sqrtf(s), 1e-12f);
  }
  __syncthreads();
  unsigned char* dst = isref ? Kb + (size_t)(mat - B_) * N_ * C_
                             : Qb + (size_t)mat * N_ * C_;
#pragma unroll
  for (int i = 0; i < 4; ++i){
    int nr = (t >> 4) + 16 * i;
    float iv = inv_sh[nr];
    unsigned char* drow = dst + (size_t)(nt * 64 + nr) * C_;
#pragma unroll
    for (int ct = 0; ct < 6; ++ct){
      int c0 = ct * 64 + (t & 15) * 4;
      uint32_t a0 = *(const uint32_t*)(&tile[nr][c0]);      // bf16 pair c0,c0+1
      uint32_t a1 = *(const uint32_t*)(&tile[nr][c0 + 2]);  // bf16 pair c0+2,+3
      uint32_t pk = pk_fp8x4(bf2f((unsigned short)(a0 & 0xffff)) * iv,
                             bf2f((unsigned short)(a0 >> 16))    * iv,
                             bf2f((unsigned short)(a1 & 0xffff)) * iv,
                             bf2f((unsigned short)(a1 >> 16))    * iv);
      *(uint32_t*)(drow + c0) = pk;
    }
  }
}

// ------------------------------------------------------------------ mask ----
__global__ void mask_kernel(const float* __restrict__ sopm,
                            float* __restrict__ maskp){
  int gid = blockIdx.x * 256 + threadIdx.x;       // 12800
  int b = gid / N_, n = gid - b * N_;
  int oy = n / HW_, ox = n - oy * HW_;
  const float* sp = sopm + (size_t)b * S_ * S_;
  float cy = oy * 4 + 1.5f, cx = ox * 4 + 1.5f;
  int y0 = 4*oy - 2; if (y0 < 0) y0 = 0;
  int y1 = 4*oy + 5; if (y1 > S_-1) y1 = S_-1;
  int x0 = 4*ox - 2; if (x0 < 0) x0 = 0;
  int x1 = 4*ox + 5; if (x1 > S_-1) x1 = S_-1;
  float wsy = 0.f, wsx = 0.f;
  for (int j = y0; j <= y1; ++j) wsy += 1.f - fabsf(j - cy) * 0.25f;
  for (int j = x0; j <= x1; ++j) wsx += 1.f - fabsf(j - cx) * 0.25f;
  float acc = 0.f;
  for (int jy = y0; jy <= y1; ++jy){
    float wy = 1.f - fabsf(jy - cy) * 0.25f;
    float rs = 0.f;
    for (int jx = x0; jx <= x1; ++jx)
      rs += (1.f - fabsf(jx - cx) * 0.25f) * sp[jy * S_ + jx];
    acc += wy * rs;
  }
  float val = acc / (wsy * wsx);
  maskp[gid] = (val > 0.3f) ? 1.f : 0.f;
}

// ------------------------------------------------------------- attention ----
// grid 800 = (r*B+b)*25 + qtile (XCD-swizzled). Block: 8 WAVES (512 thr).
// QK 2x4 wave grid: wave (mw=w>>2, qw=w&3) computes sim[mw*16..+16][qw*16..+16]
//   (one 16x16 tile, 12 MFMA, Q regs 24 VGPR). P block-shared [64q][32m] bf16.
// PV c-split 8 ways: wave w owns c = w*48..+48 (12 MFMA, acc 48 VGPR).
// K double-buffered (staged by waves 0-3), V single-buffered (all waves).
// 2 barriers/iter, full vmcnt drain before bar1:
//  QK(kb[cur]) | softmax, P-write, lgkm0+vmcnt0 | bar1 | stageK(t+2);
//  pa-read; PV(V) | bar2 | stageV(t+1)
// LDS: K 2x12K + V 24K + P 4K = 52K.
// __launch_bounds__(512,4): 4 waves/EU -> 16 waves/CU = 2 blocks/CU.
// Unified reg budget 128/wave; this kernel = 76 arch + 48 acc = 124 (R12 data).
// (R12 ran this at (512,2) = 1 block/CU -> every barrier drain stalled the CU.)
#define KB0_   0
#define KB1_   12288
#define VB_    24576
#define P_OFF  49152
#define LDS_SZ 53248

__global__ __launch_bounds__(512, 4) void attn_kernel(
    const unsigned char* __restrict__ Qb,
    const unsigned char* __restrict__ Kb,
    const unsigned short* __restrict__ Vb,
    const float* __restrict__ log_tau,
    unsigned short* __restrict__ Or)
{
  __shared__ __align__(16) char lds[LDS_SZ];
  int wg   = blockIdx.x;
  int orig = (wg & 7) * 100 + (wg >> 3);   // XCD-contiguous chunks (800 = 8*100)
  int qt   = orig % 25;
  int rb   = orig / 25;                    // r*B + b
  int b    = rb & 7;
  int tid  = threadIdx.x;
  int lane = tid & 63;
  int w    = tid >> 6;                     // 0..7
  int mw   = w >> 2;                       // m-half for QK
  int qw   = w & 3;                        // q-quarter for QK
  int l15  = lane & 15;
  int lg   = lane >> 4;

  float tau = expf(log_tau[0]);
  tau = fminf(fmaxf(tau, 0.005f), 0.1f);
  float sc = 1.4426950408889634f / tau;    // log2(e)/tau

  // Q fp8 fragments: 16 q rows in regs (24 VGPR)
  i64t qreg[12];
  {
    const unsigned char* qp = Qb +
        ((size_t)b * N_ + qt * 64 + qw * 16 + l15) * C_ + lg * 8;
#pragma unroll
    for (int ks = 0; ks < 12; ++ks)
      qreg[ks] = *(const i64t*)(qp + ks * 32);
  }

  // O accumulator: [qf2 0..3][cf 0..2] -> O[qf2*16 + lg*4 + rg][w*48 + cf*16 + l15]
  f32x4 o[4][3];
#pragma unroll
  for (int i = 0; i < 4; ++i)
#pragma unroll
    for (int j = 0; j < 3; ++j) o[i][j] = (f32x4){0.f,0.f,0.f,0.f};
  float lsum = 0.f;                        // partial l for q = qw*16+l15 (mw-half)

  const unsigned char*  kmat = Kb + (size_t)rb * N_ * C_;
  const unsigned short* vmat = Vb + (size_t)rb * C_ * N_;
  char* Pb = lds + P_OFF;                  // block-shared P [64q][64B row]

  // per-lane global byte offsets for K staging (waves 0-3 only, 3 each)
  int koffB[3];
#pragma unroll
  for (int i = 0; i < 3; ++i){
    int L = ((w & 3) * 3 + i) * 64 + lane;        // granule 0..767
    int m   = L / 24;
    int pos = L - m * 24;
    int cc  = (pos >> 3) * 8 + ((pos & 7) ^ (m & 7));
    koffB[i] = m * C_ + cc * 16;
  }
  // per-lane global element offsets for V staging (all 8 waves, 3 each)
  int voff[3];
#pragma unroll
  for (int i = 0; i < 3; ++i){
    int chunk = (w * 3 + i) * 64 + lane;          // 0..1535
    int line = chunk >> 3;
    int u    = (chunk & 7) ^ (line & 7);
    voff[i]  = (line * 2 + (u >> 2)) * N_ + (u & 3) * 8;
  }

  // P offsets: row q (64B rows), granule phys = logical ^ s(q), s = (l15>>1)&3
  const int s_l  = (l15 >> 1) & 3;
  const int p_w  = (qw*16 + l15) * 64 + (((mw*2 + (lg >> 1)) ^ s_l) << 4) + (lg & 1) * 8;
  const int p_rc = ((lg ^ s_l) << 4) + l15 * 64;   // + qf2*1024

  auto stageK = [&](int t, int buf){
    if (w < 4){
      const unsigned char* kb = kmat + (size_t)t * 32 * C_;
      char* kdst = lds + (buf ? KB1_ : KB0_) + w * 3072;
#pragma unroll
      for (int i = 0; i < 3; ++i) gload_lds16(kb + koffB[i], kdst + i * 1024);
    }
  };
  auto stageV = [&](int t){
    const unsigned short* vb = vmat + t * 32;
    char* vdst = lds + VB_ + w * 3072;
#pragma unroll
    for (int i = 0; i < 3; ++i) gload_lds16(vb + voff[i], vdst + i * 1024);
  };

  // prologue: K0 + V0 staged and drained; K1 in flight
  stageK(0, 0);
  stageV(0);
  asm volatile("s_waitcnt vmcnt(0)" ::: "memory");
  __builtin_amdgcn_sched_barrier(0);
  __builtin_amdgcn_s_barrier();
  __builtin_amdgcn_sched_barrier(0);
  stageK(1, 1);

  const int krow = (mw * 16 + l15);        // K LDS row this lane reads
  for (int mt = 0; mt < 50; ++mt){
    int cur = mt & 1;
    const char* kbR = lds + (cur ? KB1_ : KB0_);

    // ---- QK^T fp8 (swapped): sim[mw 16m][qw 16q], 12 a-loads, 12 MFMAs
    f32x4 s0 = {0.f,0.f,0.f,0.f};
    __builtin_amdgcn_s_setprio(1);
#pragma unroll
    for (int ks = 0; ks < 12; ++ks){
      int lc  = 2 * ks + (lg >> 1);
      int off = ((lc >> 3) * 8 + ((lc & 7) ^ (krow & 7))) * 16 + (lg & 1) * 8;
      i64t a = *(const i64t*)(kbR + krow * 384 + off);
      s0 = __builtin_amdgcn_mfma_f32_16x16x32_fp8_fp8(a, qreg[ks], s0, 0, 0, 0);
    }
    __builtin_amdgcn_s_setprio(0);

    // ---- P = exp2((sim-1)*log2e/tau), quantize bf16, accumulate l
    ushort4 pw;
    {
      __bf16 h;
      float l0 = 0.f;
      h = (__bf16)exp2f((s0[0]-1.f)*sc); l0 += (float)h; pw.x = __builtin_bit_cast(unsigned short, h);
      h = (__bf16)exp2f((s0[1]-1.f)*sc); l0 += (float)h; pw.y = __builtin_bit_cast(unsigned short, h);
      h = (__bf16)exp2f((s0[2]-1.f)*sc); l0 += (float)h; pw.z = __builtin_bit_cast(unsigned short, h);
      h = (__bf16)exp2f((s0[3]-1.f)*sc); l0 += (float)h; pw.w = __builtin_bit_cast(unsigned short, h);
      lsum += l0;
    }
    *(ushort4*)(Pb + p_w) = pw;     // q = qw*16+l15, m = mw*16+lg*4..+3
    // retire P-write + ALL outstanding VMEM: K(t+1) (full iter of flight)
    // and V(t) (flew through QK+softmax). Per-wave counts differ -> full drain.
    asm volatile("s_waitcnt lgkmcnt(0) vmcnt(0)" ::: "memory");
    __builtin_amdgcn_sched_barrier(0);
    __builtin_amdgcn_s_barrier();          // bar1: P visible; K(t) read; V(t) in
    __builtin_amdgcn_sched_barrier(0);

    // ---- stage K(t+2) into kb[cur] (its readers finished at bar1)
    int tk = (mt + 2 < 50) ? mt + 2 : mt;
    stageK(tk, cur);
    __builtin_amdgcn_sched_barrier(0);

    // ---- PV c-split: O[64q][w*48..+48] += P * V (P + V from LDS)
    bf16x8 pa[4];
#pragma unroll
    for (int qf2 = 0; qf2 < 4; ++qf2)
      pa[qf2] = *(const bf16x8*)(Pb + qf2 * 1024 + p_rc);  // P[qf2*16+l15][lg*8..+7]
    __builtin_amdgcn_s_setprio(1);
#pragma unroll
    for (int cf = 0; cf < 3; ++cf){
      int c  = w * 48 + cf * 16 + l15;
      int vo = (c >> 1) * 128 + (((lg | ((c & 1) << 2)) ^ ((c >> 1) & 7)) << 4);
      bf16x8 vf = *(const bf16x8*)(lds + VB_ + vo);
#pragma unroll
      for (int qf2 = 0; qf2 < 4; ++qf2)
        o[qf2][cf] = __builtin_amdgcn_mfma_f32_16x16x32_bf16(pa[qf2], vf, o[qf2][cf], 0, 0, 0);
    }
    __builtin_amdgcn_s_setprio(0);

    __builtin_amdgcn_sched_barrier(0);
    __builtin_amdgcn_s_barrier();          // bar2: V(t)/P(t) fully consumed
    __builtin_amdgcn_sched_barrier(0);

    // ---- stage V(t+1) into the single V buffer; flies through QK(t+1)
    int tv = (mt + 1 < 50) ? mt + 1 : 49;
    stageV(tv);
    __builtin_amdgcn_sched_barrier(0);
  }

  // ---- finalize: partial l (this wave's 16 m's) -> reduce over lg, then
  //      sum the two mw halves via LDS
  lsum += __shfl_xor(lsum, 16, 64);
  lsum += __shfl_xor(lsum, 32, 64);
  __syncthreads();                         // drains dead prefetches; loop done
  float* lsh = (float*)lds;                // [2 mw][64 q]
  if (lg == 0) lsh[mw * 64 + qw * 16 + l15] = lsum;
  __syncthreads();
  float invl[4][4];
#pragma unroll
  for (int qf2 = 0; qf2 < 4; ++qf2)
#pragma unroll
    for (int rg = 0; rg < 4; ++rg){
      int q = qf2 * 16 + lg * 4 + rg;
      invl[qf2][rg] = 1.f / (lsh[q] + lsh[64 + q]);
    }

  int qbase = qt * 64;
  unsigned short* op = Or + ((size_t)rb * N_ + qbase) * C_ + w * 48 + l15;
#pragma unroll
  for (int qf2 = 0; qf2 < 4; ++qf2){
#pragma unroll
    for (int cf = 0; cf < 3; ++cf){
#pragma unroll
      for (int rg = 0; rg < 4; ++rg){
        int q = qf2 * 16 + lg * 4 + rg;
        op[(size_t)q * C_ + cf * 16] = f2bf(o[qf2][cf][rg] * invl[qf2][rg]);
      }
    }
  }
}

// --------------------------------------------------------------- combine ----
// out[b][c][n] = feats + mask*alpha*(sum_r Or/4 - feats); transpose [n][c]->[c][n]
__global__ void combine_kernel(const unsigned short* __restrict__ Or,
                               const float* __restrict__ feats,
                               const float* __restrict__ maskp,
                               const float* __restrict__ alpha_raw,
                               float* __restrict__ out){
  int nt = blockIdx.x, ct = blockIdx.y, b = blockIdx.z;
  __shared__ float tile[64][65];
  float alpha = 1.f / (1.f + expf(-alpha_raw[0]));
  int t = threadIdx.x;
#pragma unroll
  for (int i = 0; i < 4; ++i){
    int chunk = t + 256 * i;
    int nr = chunk >> 4, c4 = chunk & 15;
    size_t base = ((size_t)b * N_ + nt * 64 + nr) * C_ + ct * 64 + c4 * 4;
    float4 s = {0.f,0.f,0.f,0.f};
#pragma unroll
    for (int r = 0; r < 4; ++r){
      ushort4 v = *(const ushort4*)(Or + (size_t)r * B_ * N_ * C_ + base);
      s.x += bf2f(v.x); s.y += bf2f(v.y); s.z += bf2f(v.z); s.w += bf2f(v.w);
    }
    tile[nr][c4*4+0] = s.x; tile[nr][c4*4+1] = s.y;
    tile[nr][c4*4+2] = s.z; tile[nr][c4*4+3] = s.w;
  }
  __syncthreads();
#pragma unroll
  for (int i = 0; i < 4; ++i){
    int chunk = t + 256 * i;
    int cr = chunk >> 4, n4 = chunk & 15;
    size_t fb = ((size_t)b * C_ + ct * 64 + cr) * N_ + nt * 64 + n4 * 4;
    float4 f  = *(const float4*)(feats + fb);
    float4 mk = *(const float4*)(maskp + (size_t)b * N_ + nt * 64 + n4 * 4);
    float4 ov;
    ov.x = f.x + mk.x * alpha * (tile[n4*4+0][cr] * 0.25f - f.x);
    ov.y = f.y + mk.y * alpha * (tile[n4*4+1][cr] * 0.25f - f.y);
    ov.z = f.z + mk.z * alpha * (tile[n4*4+2][cr] * 0.25f - f.z);
    ov.w = f.w + mk.w * alpha * (tile[n4*4+3][cr] * 0.25f - f.w);
    *(float4*)(out + fb) = ov;
  }
}

// ws-too-small sentinel: recognizable absmax ~1e6
__global__ void poison_kernel(float* out, int n){
  int i = blockIdx.x * 256 + threadIdx.x;
  if (i < n) out[i] = 1.0e6f;
}

extern "C" void kernel_launch(void* const* d_in, const int* in_sizes, int n_in,
                              void* d_out, int out_size, void* d_ws, size_t ws_size,
                              hipStream_t stream){
  const float* feats     = (const float*)d_in[0];
  const float* refs      = (const float*)d_in[1];
  const float* sopm      = (const float*)d_in[2];
  const float* log_tau   = (const float*)d_in[3];
  const float* alpha_raw = (const float*)d_in[4];
  float* out = (float*)d_out;

  const size_t SZ_MASK = (size_t)B_ * N_ * 4;              //    51,200
  const size_t SZ_QB   = (size_t)B_ * N_ * C_;             // 4,915,200 (fp8)
  const size_t SZ_KB   = (size_t)R_ * B_ * N_ * C_;        // 19,660,800 (fp8)
  const size_t SZ_VB   = (size_t)R_ * B_ * N_ * C_ * 2;    // 39,321,600 (bf16)
  const size_t SZ_OR   = (size_t)R_ * B_ * N_ * C_ * 2;    // 39,321,600 (bf16)
  const size_t need = SZ_MASK + SZ_QB + SZ_KB + SZ_VB + SZ_OR;

  if (ws_size < need){
    poison_kernel<<<(out_size + 255) / 256, 256, 0, stream>>>(out, out_size);
    return;
  }
  char* ws = (char*)d_ws;
  float*          maskp = (float*)ws;
  unsigned char*  Qb    = (unsigned char*)(ws + SZ_MASK);
  unsigned char*  Kb    = (unsigned char*)(ws + SZ_MASK + SZ_QB);
  unsigned short* Vb    = (unsigned short*)(ws + SZ_MASK + SZ_QB + SZ_KB);
  unsigned short* Or    = (unsigned short*)(ws + SZ_MASK + SZ_QB + SZ_KB + SZ_VB);

  mask_kernel   <<<50, 256, 0, stream>>>(sopm, maskp);
  prep_kernel   <<<dim3(25, 40), 256, 0, stream>>>(feats, refs, Qb, Kb, Vb);
  attn_kernel   <<<800, 512, 0, stream>>>(Qb, Kb, Vb, log_tau, Or);
  combine_kernel<<<dim3(25, 6, 8), 256, 0, stream>>>(Or, feats, maskp, alpha_raw, out);
}

// Round 15
// 215.164 us; speedup vs baseline: 1.0112x; 1.0112x over previous
//
#include <hip/hip_runtime.h>
#include <stdint.h>

// Problem constants (fixed by reference)
#define B_  8
#define C_  384
#define N_  1600
#define R_  4
#define S_  160
#define HW_ 40

typedef float  f32x4  __attribute__((ext_vector_type(4)));
typedef __bf16 bf16x8 __attribute__((ext_vector_type(8)));
typedef long long i64t;

__device__ __forceinline__ unsigned short f2bf(float x){
  __bf16 h = (__bf16)x;                         // RNE
  return __builtin_bit_cast(unsigned short, h);
}
__device__ __forceinline__ float bf2f(unsigned short u){
  return __builtin_bit_cast(float, (uint32_t)u << 16);
}
// pack 4 floats -> 4 OCP e4m3 bytes (v_cvt_pk_fp8_f32 on gfx950 emits OCP)
__device__ __forceinline__ uint32_t pk_fp8x4(float a, float b, float c, float d){
  int lo = __builtin_amdgcn_cvt_pk_fp8_f32(a, b, 0, false);
  int hi = __builtin_amdgcn_cvt_pk_fp8_f32(c, d, 0, false);
  return (uint32_t)(lo & 0xffff) | ((uint32_t)hi << 16);
}

// async global->LDS, 16B per lane; LDS dest is wave-uniform base + lane*16
__device__ __forceinline__ void gload_lds16(const void* g, void* l){
  __builtin_amdgcn_global_load_lds(
      (const __attribute__((address_space(1))) uint32_t*)g,
      (__attribute__((address_space(3))) uint32_t*)l, 16, 0, 0);
}

// ------------------------------------------- fused norm + transpose/convert ----
// One block per (nt, mat): reads the 64n x 384c f32 tile ONCE, writes V bf16
// inline, computes row norms from registers+LDS partials, then emits
// Q/K fp8 [n][c] from the bf16 LDS tile.
__global__ void prep_kernel(const float* __restrict__ feats,
                            const float* __restrict__ refs,
                            unsigned char* __restrict__ Qb,
                            unsigned char* __restrict__ Kb,
                            unsigned short* __restrict__ Vb){
  int nt = blockIdx.x, mat = blockIdx.y;
  __shared__ unsigned short tile[64][386];   // [n][c] bf16; 772B rows (odd dwords)
  __shared__ float ssp[64][17];              // per-n partial sums (16 producers)
  __shared__ float inv_sh[64];
  int t = threadIdx.x;
  bool isref = (mat >= B_);
  const float* src = isref ? refs  + (size_t)(mat - B_) * C_ * N_
                           : feats + (size_t)mat * C_ * N_;
  int n4  = t & 15;        // owns n = n4*4 .. +3 (fixed per thread)
  int crb = t >> 4;        // c-row base 0..15
  float ss4[4] = {0.f, 0.f, 0.f, 0.f};
#pragma unroll
  for (int ct = 0; ct < 6; ++ct){
#pragma unroll
    for (int i = 0; i < 4; ++i){
      int c = ct * 64 + crb + 16 * i;
      size_t off = (size_t)c * N_ + nt * 64 + n4 * 4;
      float4 v = *(const float4*)(src + off);
      ushort4 o;
      o.x = f2bf(v.x); o.y = f2bf(v.y); o.z = f2bf(v.z); o.w = f2bf(v.w);
      if (isref){
        unsigned short* vdst = Vb + (size_t)(mat - B_) * C_ * N_;
        *(ushort4*)(vdst + off) = o;       // V = raw bf16, same [c][n] layout
      }
      tile[n4*4+0][c] = o.x;
      tile[n4*4+1][c] = o.y;
      tile[n4*4+2][c] = o.z;
      tile[n4*4+3][c] = o.w;
      ss4[0] += v.x * v.x;  ss4[1] += v.y * v.y;
      ss4[2] += v.z * v.z;  ss4[3] += v.w * v.w;
    }
  }
#pragma unroll
  for (int j = 0; j < 4; ++j) ssp[n4*4+j][crb] = ss4[j];
  __syncthreads();
  if (t < 64){
    float s = 0.f;
#pragma unroll
    for (int p = 0; p < 16; ++p) s += ssp[t][p];
    inv_sh[t] = 1.f / fmaxf(sqrtf(s), 1e-12f);
  }
  __syncthreads();
  unsigned char* dst = isref ? Kb + (size_t)(mat - B_) * N_ * C_
                             : Qb + (size_t)mat * N_ * C_;
#pragma unroll
  for (int i = 0; i < 4; ++i){
    int nr = (t >> 4) + 16 * i;
    float iv = inv_sh[nr];
    unsigned char* drow = dst + (size_t)(nt * 64 + nr) * C_;
#pragma unroll
    for (int ct = 0; ct < 6; ++ct){
      int c0 = ct * 64 + (t & 15) * 4;
      uint32_t a0 = *(const uint32_t*)(&tile[nr][c0]);      // bf16 pair c0,c0+1
      uint32_t a1 = *(const uint32_t*)(&tile[nr][c0 + 2]);  // bf16 pair c0+2,+3
      uint32_t pk = pk_fp8x4(bf2f((unsigned short)(a0 & 0xffff)) * iv,
                             bf2f((unsigned short)(a0 >> 16))    * iv,
                             bf2f((unsigned short)(a1 & 0xffff)) * iv,
                             bf2f((unsigned short)(a1 >> 16))    * iv);
      *(uint32_t*)(drow + c0) = pk;
    }
  }
}

// ------------------------------------------------------------------ mask ----
__global__ void mask_kernel(const float* __restrict__ sopm,
                            float* __restrict__ maskp){
  int gid = blockIdx.x * 256 + threadIdx.x;       // 12800
  int b = gid / N_, n = gid - b * N_;
  int oy = n / HW_, ox = n - oy * HW_;
  const float* sp = sopm + (size_t)b * S_ * S_;
  float cy = oy * 4 + 1.5f, cx = ox * 4 + 1.5f;
  int y0 = 4*oy - 2; if (y0 < 0) y0 = 0;
  int y1 = 4*oy + 5; if (y1 > S_-1) y1 = S_-1;
  int x0 = 4*ox - 2; if (x0 < 0) x0 = 0;
  int x1 = 4*ox + 5; if (x1 > S_-1) x1 = S_-1;
  float wsy = 0.f, wsx = 0.f;
  for (int j = y0; j <= y1; ++j) wsy += 1.f - fabsf(j - cy) * 0.25f;
  for (int j = x0; j <= x1; ++j) wsx += 1.f - fabsf(j - cx) * 0.25f;
  float acc = 0.f;
  for (int jy = y0; jy <= y1; ++jy){
    float wy = 1.f - fabsf(jy - cy) * 0.25f;
    float rs = 0.f;
    for (int jx = x0; jx <= x1; ++jx)
      rs += (1.f - fabsf(jx - cx) * 0.25f) * sp[jy * S_ + jx];
    acc += wy * rs;
  }
  float val = acc / (wsy * wsx);
  maskp[gid] = (val > 0.3f) ? 1.f : 0.f;
}

// ------------------------------------------------------------- attention ----
// grid 800 = (r*B+b)*25 + qtile (XCD-swizzled). Block: 4 waves. KVBLK=64:
// 25 iters (not 50) to amortize per-iter barrier/sync fixed cost.
// QK 2x2 wave-split: wave (mw,qw) computes sim[mw*32..+32][qw*32..+32]
//   (4 16x16 fragments, 48 MFMA). P block-shared [64q][64m] bf16 (8KB,
//   granule-XOR swizzled 128B rows). PV c-split: wave w owns c=w*96..+96,
//   2 m-slices per cf (48 MFMA). K single-buffered (24KB), V single (48KB).
// 3 barriers/iter: QK | softmax,P-write, lgkm0+vmcnt0 | bar1 | stageK(t+1) |
//   pa, PV | bar2 | stageV(t+1), vmcnt(12) [retire K only] | bar3.
// LDS 81920 = K 24K + V 48K + P 8K -> exactly 2 blocks/CU (160KB).
#define KB_    0
#define VB_    24576
#define P_OFF  73728
#define LDS_SZ 81920

__global__ __launch_bounds__(256, 2) void attn_kernel(
    const unsigned char* __restrict__ Qb,
    const unsigned char* __restrict__ Kb,
    const unsigned short* __restrict__ Vb,
    const float* __restrict__ log_tau,
    unsigned short* __restrict__ Or)
{
  __shared__ __align__(16) char lds[LDS_SZ];
  int wg   = blockIdx.x;
  int orig = (wg & 7) * 100 + (wg >> 3);   // XCD-contiguous chunks (800 = 8*100)
  int qt   = orig % 25;
  int rb   = orig / 25;                    // r*B + b
  int b    = rb & 7;
  int tid  = threadIdx.x;
  int lane = tid & 63;
  int w    = tid >> 6;
  int mw   = w >> 1;                       // m-half (32 rows) for QK
  int qw   = w & 1;                        // q-half (32 rows) for QK
  int l15  = lane & 15;
  int lg   = lane >> 4;
  const int s7 = l15 & 7;                  // row-XOR key (all swizzles)

  float tau = expf(log_tau[0]);
  tau = fminf(fmaxf(tau, 0.005f), 0.1f);
  float sc = 1.4426950408889634f / tau;    // log2(e)/tau

  // Q fp8 fragments: 32 q rows (2 q-tiles) in regs (48 VGPR)
  i64t qreg[2][12];
#pragma unroll
  for (int qt2 = 0; qt2 < 2; ++qt2){
    const unsigned char* qp = Qb +
        ((size_t)b * N_ + qt * 64 + qw * 32 + qt2 * 16 + l15) * C_ + lg * 8;
#pragma unroll
    for (int ks = 0; ks < 12; ++ks)
      qreg[qt2][ks] = *(const i64t*)(qp + ks * 32);
  }

  // O accumulator: [qf2 0..3][cf 0..5] -> O[qf2*16 + lg*4 + rg][w*96 + cf*16 + l15]
  f32x4 o[4][6];
#pragma unroll
  for (int i = 0; i < 4; ++i)
#pragma unroll
    for (int j = 0; j < 6; ++j) o[i][j] = (f32x4){0.f,0.f,0.f,0.f};
  float lsum0 = 0.f, lsum1 = 0.f;          // l for q = qw*32 + {l15, 16+l15}

  const unsigned char*  kmat = Kb + (size_t)rb * N_ * C_;
  const unsigned short* vmat = Vb + (size_t)rb * C_ * N_;
  char* Pb = lds + P_OFF;                  // block-shared P [64q][128B row]

  // K staging: 1536 granules -> 6 gload_lds per wave; row m (0..63), 24 gran/row
  int koffB[6];
#pragma unroll
  for (int i = 0; i < 6; ++i){
    int L = (w * 6 + i) * 64 + lane;
    int m   = L / 24;
    int pos = L - m * 24;
    int cc  = (pos >> 3) * 8 + ((pos & 7) ^ (m & 7));
    koffB[i] = m * C_ + cc * 16;
  }
  // V staging: 3072 granules -> 12 per wave; row c (128B = 8 gran), XOR(c&7)
  int voff[12];
#pragma unroll
  for (int i = 0; i < 12; ++i){
    int chunk = (w * 12 + i) * 64 + lane;
    int c = chunk >> 3;
    int u = (chunk & 7) ^ (c & 7);
    voff[i] = c * N_ + u * 8;              // elements (ushort)
  }

  // P write offsets [mi][qi]: row q=qw*32+qi*16+l15 (128B), logical granule
  // = mw*4+mi*2+(lg>>1), half lg&1; phys = logical ^ (q&7) = ^ s7
  int p_wo[2][2];
#pragma unroll
  for (int mi = 0; mi < 2; ++mi)
#pragma unroll
    for (int qi = 0; qi < 2; ++qi)
      p_wo[mi][qi] = (qw*32 + qi*16 + l15) * 128 +
                     (((mw*4 + mi*2 + (lg >> 1)) ^ s7) << 4) + (lg & 1) * 8;

  auto stageK = [&](int t){
    const unsigned char* kb = kmat + (size_t)t * 64 * C_;
#pragma unroll
    for (int i = 0; i < 6; ++i)
      gload_lds16(kb + koffB[i], lds + KB_ + (w * 6 + i) * 1024);
  };
  auto stageV = [&](int t){
    const unsigned short* vb = vmat + t * 64;
#pragma unroll
    for (int i = 0; i < 12; ++i)
      gload_lds16(vb + voff[i], lds + VB_ + (w * 12 + i) * 1024);
  };

  // prologue: K0 + V0 staged and drained
  stageK(0);
  stageV(0);
  asm volatile("s_waitcnt vmcnt(0)" ::: "memory");
  __builtin_amdgcn_sched_barrier(0);
  __builtin_amdgcn_s_barrier();
  __builtin_amdgcn_sched_barrier(0);

  const int krow0 = (mw * 32 + l15) * 384;        // K LDS rows this lane reads
  const int krow1 = (mw * 32 + 16 + l15) * 384;
  for (int mt = 0; mt < 25; ++mt){
    // ---- QK^T fp8 (swapped): sim[mw 32m][qw 32q], 24 a-loads, 48 MFMAs
    f32x4 s00 = {0.f,0.f,0.f,0.f}, s01 = {0.f,0.f,0.f,0.f};
    f32x4 s10 = {0.f,0.f,0.f,0.f}, s11 = {0.f,0.f,0.f,0.f};
    __builtin_amdgcn_s_setprio(1);
#pragma unroll
    for (int ks = 0; ks < 12; ++ks){
      int lc  = 2 * ks + (lg >> 1);
      int off = ((lc >> 3) * 8 + ((lc & 7) ^ s7)) * 16 + (lg & 1) * 8;
      i64t a0 = *(const i64t*)(lds + KB_ + krow0 + off);
      i64t a1 = *(const i64t*)(lds + KB_ + krow1 + off);
      s00 = __builtin_amdgcn_mfma_f32_16x16x32_fp8_fp8(a0, qreg[0][ks], s00, 0, 0, 0);
      s01 = __builtin_amdgcn_mfma_f32_16x16x32_fp8_fp8(a0, qreg[1][ks], s01, 0, 0, 0);
      s10 = __builtin_amdgcn_mfma_f32_16x16x32_fp8_fp8(a1, qreg[0][ks], s10, 0, 0, 0);
      s11 = __builtin_amdgcn_mfma_f32_16x16x32_fp8_fp8(a1, qreg[1][ks], s11, 0, 0, 0);
    }
    __builtin_amdgcn_s_setprio(0);

    // ---- P = exp2((sim-1)*log2e/tau) -> bf16; accumulate l per q
    {
      __bf16 h;
      float l0 = 0.f, l1 = 0.f;
      ushort4 pw;
      h = (__bf16)exp2f((s00[0]-1.f)*sc); l0 += (float)h; pw.x = __builtin_bit_cast(unsigned short, h);
      h = (__bf16)exp2f((s00[1]-1.f)*sc); l0 += (float)h; pw.y = __builtin_bit_cast(unsigned short, h);
      h = (__bf16)exp2f((s00[2]-1.f)*sc); l0 += (float)h; pw.z = __builtin_bit_cast(unsigned short, h);
      h = (__bf16)exp2f((s00[3]-1.f)*sc); l0 += (float)h; pw.w = __builtin_bit_cast(unsigned short, h);
      *(ushort4*)(Pb + p_wo[0][0]) = pw;   // mi=0, qi=0
      h = (__bf16)exp2f((s01[0]-1.f)*sc); l1 += (float)h; pw.x = __builtin_bit_cast(unsigned short, h);
      h = (__bf16)exp2f((s01[1]-1.f)*sc); l1 += (float)h; pw.y = __builtin_bit_cast(unsigned short, h);
      h = (__bf16)exp2f((s01[2]-1.f)*sc); l1 += (float)h; pw.z = __builtin_bit_cast(unsigned short, h);
      h = (__bf16)exp2f((s01[3]-1.f)*sc); l1 += (float)h; pw.w = __builtin_bit_cast(unsigned short, h);
      *(ushort4*)(Pb + p_wo[0][1]) = pw;   // mi=0, qi=1
      h = (__bf16)exp2f((s10[0]-1.f)*sc); l0 += (float)h; pw.x = __builtin_bit_cast(unsigned short, h);
      h = (__bf16)exp2f((s10[1]-1.f)*sc); l0 += (float)h; pw.y = __builtin_bit_cast(unsigned short, h);
      h = (__bf16)exp2f((s10[2]-1.f)*sc); l0 += (float)h; pw.z = __builtin_bit_cast(unsigned short, h);
      h = (__bf16)exp2f((s10[3]-1.f)*sc); l0 += (float)h; pw.w = __builtin_bit_cast(unsigned short, h);
      *(ushort4*)(Pb + p_wo[1][0]) = pw;   // mi=1, qi=0
      h = (__bf16)exp2f((s11[0]-1.f)*sc); l1 += (float)h; pw.x = __builtin_bit_cast(unsigned short, h);
      h = (__bf16)exp2f((s11[1]-1.f)*sc); l1 += (float)h; pw.y = __builtin_bit_cast(unsigned short, h);
      h = (__bf16)exp2f((s11[2]-1.f)*sc); l1 += (float)h; pw.z = __builtin_bit_cast(unsigned short, h);
      h = (__bf16)exp2f((s11[3]-1.f)*sc); l1 += (float)h; pw.w = __builtin_bit_cast(unsigned short, h);
      *(ushort4*)(Pb + p_wo[1][1]) = pw;   // mi=1, qi=1
      lsum0 += l0; lsum1 += l1;
    }
    // retire P-writes + K-reads (lgkm) and V(t) loads (vmcnt; >=1 iter flight)
    asm volatile("s_waitcnt lgkmcnt(0) vmcnt(0)" ::: "memory");
    __builtin_amdgcn_sched_barrier(0);
    __builtin_amdgcn_s_barrier();          // bar1: P visible; K(t) fully read
    __builtin_amdgcn_sched_barrier(0);

    // ---- stage K(t+1) into the single K buffer (readers finished at bar1)
    int tk = (mt + 1 < 25) ? mt + 1 : mt;
    stageK(tk);
    __builtin_amdgcn_sched_barrier(0);

    // ---- PV c-split: O[64q][w*96..+96] += P * V (P + V from LDS)
    bf16x8 pa[4][2];
#pragma unroll
    for (int qf2 = 0; qf2 < 4; ++qf2)
#pragma unroll
      for (int s = 0; s < 2; ++s)
        pa[qf2][s] = *(const bf16x8*)(Pb + (qf2*16 + l15) * 128 +
                                      (((s*4 + lg) ^ s7) << 4));
    __builtin_amdgcn_s_setprio(1);
#pragma unroll
    for (int cf = 0; cf < 6; ++cf){
      int vbase = VB_ + (w*96 + cf*16 + l15) * 128;
#pragma unroll
      for (int s = 0; s < 2; ++s){
        bf16x8 vf = *(const bf16x8*)(lds + vbase + (((s*4 + lg) ^ s7) << 4));
#pragma unroll
        for (int qf2 = 0; qf2 < 4; ++qf2)
          o[qf2][cf] = __builtin_amdgcn_mfma_f32_16x16x32_bf16(pa[qf2][s], vf, o[qf2][cf], 0, 0, 0);
      }
    }
    __builtin_amdgcn_s_setprio(0);

    __builtin_amdgcn_sched_barrier(0);
    __builtin_amdgcn_s_barrier();          // bar2: V(t)/P(t) fully consumed
    __builtin_amdgcn_sched_barrier(0);

    // ---- stage V(t+1); retire only K(t+1) (oldest 6), V stays in flight
    int tv = (mt + 1 < 25) ? mt + 1 : mt;
    stageV(tv);
    asm volatile("s_waitcnt vmcnt(12)" ::: "memory");
    __builtin_amdgcn_sched_barrier(0);
    __builtin_amdgcn_s_barrier();          // bar3: K(t+1) ready for all waves
    __builtin_amdgcn_sched_barrier(0);
  }

  // ---- finalize: l per q = sum over both m-half waves
  lsum0 += __shfl_xor(lsum0, 16, 64);
  lsum0 += __shfl_xor(lsum0, 32, 64);
  lsum1 += __shfl_xor(lsum1, 16, 64);
  lsum1 += __shfl_xor(lsum1, 32, 64);
  __syncthreads();                         // drains dead prefetches; loop done
  float* lsh = (float*)lds;                // [2 mw][64 q]
  if (lg == 0){
    lsh[mw * 64 + qw * 32 + l15]      = lsum0;
    lsh[mw * 64 + qw * 32 + 16 + l15] = lsum1;
  }
  __syncthreads();
  float invl[4][4];
#pragma unroll
  for (int qf2 = 0; qf2 < 4; ++qf2)
#pragma unroll
    for (int rg = 0; rg < 4; ++rg){
      int q = qf2 * 16 + lg * 4 + rg;
      invl[qf2][rg] = 1.f / (lsh[q] + lsh[64 + q]);
    }

  int qbase = qt * 64;
  unsigned short* op = Or + ((size_t)rb * N_ + qbase) * C_ + w * 96 + l15;
#pragma unroll
  for (int qf2 = 0; qf2 < 4; ++qf2){
#pragma unroll
    for (int cf = 0; cf < 6; ++cf){
#pragma unroll
      for (int rg = 0; rg < 4; ++rg){
        int q = qf2 * 16 + lg * 4 + rg;
        op[(size_t)q * C_ + cf * 16] = f2bf(o[qf2][cf][rg] * invl[qf2][rg]);
      }
    }
  }
}

// --------------------------------------------------------------- combine ----
// out[b][c][n] = feats + mask*alpha*(sum_r Or/4 - feats); transpose [n][c]->[c][n]
__global__ void combine_kernel(const unsigned short* __restrict__ Or,
                               const float* __restrict__ feats,
                               const float* __restrict__ maskp,
                               const float* __restrict__ alpha_raw,
                               float* __restrict__ out){
  int nt = blockIdx.x, ct = blockIdx.y, b = blockIdx.z;
  __shared__ float tile[64][65];
  float alpha = 1.f / (1.f + expf(-alpha_raw[0]));
  int t = threadIdx.x;
#pragma unroll
  for (int i = 0; i < 4; ++i){
    int chunk = t + 256 * i;
    int nr = chunk >> 4, c4 = chunk & 15;
    size_t base = ((size_t)b * N_ + nt * 64 + nr) * C_ + ct * 64 + c4 * 4;
    float4 s = {0.f,0.f,0.f,0.f};
#pragma unroll
    for (int r = 0; r < 4; ++r){
      ushort4 v = *(const ushort4*)(Or + (size_t)r * B_ * N_ * C_ + base);
      s.x += bf2f(v.x); s.y += bf2f(v.y); s.z += bf2f(v.z); s.w += bf2f(v.w);
    }
    tile[nr][c4*4+0] = s.x; tile[nr][c4*4+1] = s.y;
    tile[nr][c4*4+2] = s.z; tile[nr][c4*4+3] = s.w;
  }
  __syncthreads();
#pragma unroll
  for (int i = 0; i < 4; ++i){
    int chunk = t + 256 * i;
    int cr = chunk >> 4, n4 = chunk & 15;
    size_t fb = ((size_t)b * C_ + ct * 64 + cr) * N_ + nt * 64 + n4 * 4;
    float4 f  = *(const float4*)(feats + fb);
    float4 mk = *(const float4*)(maskp + (size_t)b * N_ + nt * 64 + n4 * 4);
    float4 ov;
    ov.x = f.x + mk.x * alpha * (tile[n4*4+0][cr] * 0.25f - f.x);
    ov.y = f.y + mk.y * alpha * (tile[n4*4+1][cr] * 0.25f - f.y);
    ov.z = f.z + mk.z * alpha * (tile[n4*4+2][cr] * 0.25f - f.z);
    ov.w = f.w + mk.w * alpha * (tile[n4*4+3][cr] * 0.25f - f.w);
    *(float4*)(out + fb) = ov;
  }
}

// ws-too-small sentinel: recognizable absmax ~1e6
__global__ void poison_kernel(float* out, int n){
  int i = blockIdx.x * 256 + threadIdx.x;
  if (i < n) out[i] = 1.0e6f;
}

extern "C" void kernel_launch(void* const* d_in, const int* in_sizes, int n_in,
                              void* d_out, int out_size, void* d_ws, size_t ws_size,
                              hipStream_t stream){
  const float* feats     = (const float*)d_in[0];
  const float* refs      = (const float*)d_in[1];
  const float* sopm      = (const float*)d_in[2];
  const float* log_tau   = (const float*)d_in[3];
  const float* alpha_raw = (const float*)d_in[4];
  float* out = (float*)d_out;

  const size_t SZ_MASK = (size_t)B_ * N_ * 4;              //    51,200
  const size_t SZ_QB   = (size_t)B_ * N_ * C_;             // 4,915,200 (fp8)
  const size_t SZ_KB   = (size_t)R_ * B_ * N_ * C_;        // 19,660,800 (fp8)
  const size_t SZ_VB   = (size_t)R_ * B_ * N_ * C_ * 2;    // 39,321,600 (bf16)
  const size_t SZ_OR   = (size_t)R_ * B_ * N_ * C_ * 2;    // 39,321,600 (bf16)
  const size_t need = SZ_MASK + SZ_QB + SZ_KB + SZ_VB + SZ_OR;

  if (ws_size < need){
    poison_kernel<<<(out_size + 255) / 256, 256, 0, stream>>>(out, out_size);
    return;
  }
  char* ws = (char*)d_ws;
  float*          maskp = (float*)ws;
  unsigned char*  Qb    = (unsigned char*)(ws + SZ_MASK);
  unsigned char*  Kb    = (unsigned char*)(ws + SZ_MASK + SZ_QB);
  unsigned short* Vb    = (unsigned short*)(ws + SZ_MASK + SZ_QB + SZ_KB);
  unsigned short* Or    = (unsigned short*)(ws + SZ_MASK + SZ_QB + SZ_KB + SZ_VB);

  mask_kernel   <<<50, 256, 0, stream>>>(sopm, maskp);
  prep_kernel   <<<dim3(25, 40), 256, 0, stream>>>(feats, refs, Qb, Kb, Vb);
  attn_kernel   <<<800, 256, 0, stream>>>(Qb, Kb, Vb, log_tau, Or);
  combine_kernel<<<dim3(25, 6, 8), 256, 0, stream>>>(Or, feats, maskp, alpha_raw, out);
}

// Round 16
// 202.354 us; speedup vs baseline: 1.0752x; 1.0633x over previous
//
#include <hip/hip_runtime.h>
#include <stdint.h>

// Problem constants (fixed by reference)
#define B_  8
#define C_  384
#define N_  1600
#define R_  4
#define S_  160
#define HW_ 40

typedef float  f32x4  __attribute__((ext_vector_type(4)));
typedef __bf16 bf16x8 __attribute__((ext_vector_type(8)));
typedef long long i64t;

__device__ __forceinline__ unsigned short f2bf(float x){
  __bf16 h = (__bf16)x;                         // RNE
  return __builtin_bit_cast(unsigned short, h);
}
__device__ __forceinline__ float bf2f(unsigned short u){
  return __builtin_bit_cast(float, (uint32_t)u << 16);
}
// pack 4 floats -> 4 OCP e4m3 bytes (v_cvt_pk_fp8_f32 on gfx950 emits OCP)
__device__ __forceinline__ uint32_t pk_fp8x4(float a, float b, float c, float d){
  int lo = __builtin_amdgcn_cvt_pk_fp8_f32(a, b, 0, false);
  int hi = __builtin_amdgcn_cvt_pk_fp8_f32(c, d, 0, false);
  return (uint32_t)(lo & 0xffff) | ((uint32_t)hi << 16);
}

// async global->LDS, 16B per lane; LDS dest is wave-uniform base + lane*16
__device__ __forceinline__ void gload_lds16(const void* g, void* l){
  __builtin_amdgcn_global_load_lds(
      (const __attribute__((address_space(1))) uint32_t*)g,
      (__attribute__((address_space(3))) uint32_t*)l, 16, 0, 0);
}

// ------------------------------------------- fused norm + transpose/convert ----
// One block per (nt, mat): reads the 64n x 384c f32 tile ONCE, writes V bf16
// inline, computes row norms from registers+LDS partials, then emits
// Q/K fp8 [n][c] from the bf16 LDS tile.
__global__ void prep_kernel(const float* __restrict__ feats,
                            const float* __restrict__ refs,
                            unsigned char* __restrict__ Qb,
                            unsigned char* __restrict__ Kb,
                            unsigned short* __restrict__ Vb){
  int nt = blockIdx.x, mat = blockIdx.y;
  __shared__ unsigned short tile[64][386];   // [n][c] bf16; 772B rows (odd dwords)
  __shared__ float ssp[64][17];              // per-n partial sums (16 producers)
  __shared__ float inv_sh[64];
  int t = threadIdx.x;
  bool isref = (mat >= B_);
  const float* src = isref ? refs  + (size_t)(mat - B_) * C_ * N_
                           : feats + (size_t)mat * C_ * N_;
  int n4  = t & 15;        // owns n = n4*4 .. +3 (fixed per thread)
  int crb = t >> 4;        // c-row base 0..15
  float ss4[4] = {0.f, 0.f, 0.f, 0.f};
#pragma unroll
  for (int ct = 0; ct < 6; ++ct){
#pragma unroll
    for (int i = 0; i < 4; ++i){
      int c = ct * 64 + crb + 16 * i;
      size_t off = (size_t)c * N_ + nt * 64 + n4 * 4;
      float4 v = *(const float4*)(src + off);
      ushort4 o;
      o.x = f2bf(v.x); o.y = f2bf(v.y); o.z = f2bf(v.z); o.w = f2bf(v.w);
      if (isref){
        unsigned short* vdst = Vb + (size_t)(mat - B_) * C_ * N_;
        *(ushort4*)(vdst + off) = o;       // V = raw bf16, same [c][n] layout
      }
      tile[n4*4+0][c] = o.x;
      tile[n4*4+1][c] = o.y;
      tile[n4*4+2][c] = o.z;
      tile[n4*4+3][c] = o.w;
      ss4[0] += v.x * v.x;  ss4[1] += v.y * v.y;
      ss4[2] += v.z * v.z;  ss4[3] += v.w * v.w;
    }
  }
#pragma unroll
  for (int j = 0; j < 4; ++j) ssp[n4*4+j][crb] = ss4[j];
  __syncthreads();
  if (t < 64){
    float s = 0.f;
#pragma unroll
    for (int p = 0; p < 16; ++p) s += ssp[t][p];
    inv_sh[t] = 1.f / fmaxf(sqrtf(s), 1e-12f);
  }
  __syncthreads();
  unsigned char* dst = isref ? Kb + (size_t)(mat - B_) * N_ * C_
                             : Qb + (size_t)mat * N_ * C_;
#pragma unroll
  for (int i = 0; i < 4; ++i){
    int nr = (t >> 4) + 16 * i;
    float iv = inv_sh[nr];
    unsigned char* drow = dst + (size_t)(nt * 64 + nr) * C_;
#pragma unroll
    for (int ct = 0; ct < 6; ++ct){
      int c0 = ct * 64 + (t & 15) * 4;
      uint32_t a0 = *(const uint32_t*)(&tile[nr][c0]);      // bf16 pair c0,c0+1
      uint32_t a1 = *(const uint32_t*)(&tile[nr][c0 + 2]);  // bf16 pair c0+2,+3
      uint32_t pk = pk_fp8x4(bf2f((unsigned short)(a0 & 0xffff)) * iv,
                             bf2f((unsigned short)(a0 >> 16))    * iv,
                             bf2f((unsigned short)(a1 & 0xffff)) * iv,
                             bf2f((unsigned short)(a1 >> 16))    * iv);
      *(uint32_t*)(drow + c0) = pk;
    }
  }
}

// ------------------------------------------------------------------ mask ----
__global__ void mask_kernel(const float* __restrict__ sopm,
                            float* __restrict__ maskp){
  int gid = blockIdx.x * 256 + threadIdx.x;       // 12800
  int b = gid / N_, n = gid - b * N_;
  int oy = n / HW_, ox = n - oy * HW_;
  const float* sp = sopm + (size_t)b * S_ * S_;
  float cy = oy * 4 + 1.5f, cx = ox * 4 + 1.5f;
  int y0 = 4*oy - 2; if (y0 < 0) y0 = 0;
  int y1 = 4*oy + 5; if (y1 > S_-1) y1 = S_-1;
  int x0 = 4*ox - 2; if (x0 < 0) x0 = 0;
  int x1 = 4*ox + 5; if (x1 > S_-1) x1 = S_-1;
  float wsy = 0.f, wsx = 0.f;
  for (int j = y0; j <= y1; ++j) wsy += 1.f - fabsf(j - cy) * 0.25f;
  for (int j = x0; j <= x1; ++j) wsx += 1.f - fabsf(j - cx) * 0.25f;
  float acc = 0.f;
  for (int jy = y0; jy <= y1; ++jy){
    float wy = 1.f - fabsf(jy - cy) * 0.25f;
    float rs = 0.f;
    for (int jx = x0; jx <= x1; ++jx)
      rs += (1.f - fabsf(jx - cx) * 0.25f) * sp[jy * S_ + jx];
    acc += wy * rs;
  }
  float val = acc / (wsy * wsx);
  maskp[gid] = (val > 0.3f) ? 1.f : 0.f;
}

// ------------------------------------------------------------- attention ----
// (R10/R13 proven configuration — 171 us)
// grid 800 = (r*B+b)*25 + qtile (XCD-swizzled). Block: 4 waves.
// QK 2x2 wave-split: wave (mw=w>>1, qw=w&1) computes sim[mw*16..+16][qw*32..+32].
// P block-shared [64q][32m] bf16 (swizzled). PV c-split: wave w owns c=w*96..+96;
// V in LDS (each byte read once). K double-buffered, V SINGLE-buffered:
//  iter t: QK(kb[cur]) | softmax | P-write, lgkm0, vmcnt(0) [K(t+1),V(t) land]
//  | bar1 | stageK(t+2)->kb[cur]; pa-read; PV(V) | bar2 | stageV(t+1)
#define KB0_   0
#define KB1_   12288
#define VB_    24576
#define P_OFF  49152
#define LDS_SZ 53248

__global__ __launch_bounds__(256, 2) void attn_kernel(
    const unsigned char* __restrict__ Qb,
    const unsigned char* __restrict__ Kb,
    const unsigned short* __restrict__ Vb,
    const float* __restrict__ log_tau,
    unsigned short* __restrict__ Or)
{
  __shared__ __align__(16) char lds[LDS_SZ];
  int wg   = blockIdx.x;
  int orig = (wg & 7) * 100 + (wg >> 3);   // XCD-contiguous chunks (800 = 8*100)
  int qt   = orig % 25;
  int rb   = orig / 25;                    // r*B + b
  int b    = rb & 7;
  int tid  = threadIdx.x;
  int lane = tid & 63;
  int w    = tid >> 6;
  int mw   = w >> 1;                       // m-half for QK
  int qw   = w & 1;                        // q-half for QK
  int l15  = lane & 15;
  int lg   = lane >> 4;

  float tau = expf(log_tau[0]);
  tau = fminf(fmaxf(tau, 0.005f), 0.1f);
  float sc = 1.4426950408889634f / tau;    // log2(e)/tau

  // Q fp8 fragments: 32 q rows (2 q-tiles) in regs (48 VGPR)
  i64t qreg[2][12];
#pragma unroll
  for (int qt2 = 0; qt2 < 2; ++qt2){
    const unsigned char* qp = Qb +
        ((size_t)b * N_ + qt * 64 + qw * 32 + qt2 * 16 + l15) * C_ + lg * 8;
#pragma unroll
    for (int ks = 0; ks < 12; ++ks)
      qreg[qt2][ks] = *(const i64t*)(qp + ks * 32);
  }

  // O accumulator: [qf2 0..3][cf 0..5] -> O[qf2*16 + lg*4 + rg][w*96 + cf*16 + l15]
  f32x4 o[4][6];
#pragma unroll
  for (int i = 0; i < 4; ++i)
#pragma unroll
    for (int j = 0; j < 6; ++j) o[i][j] = (f32x4){0.f,0.f,0.f,0.f};
  float lsum0 = 0.f, lsum1 = 0.f;          // l for q = qw*32 + {l15, 16+l15}

  const unsigned char*  kmat = Kb + (size_t)rb * N_ * C_;
  const unsigned short* vmat = Vb + (size_t)rb * C_ * N_;
  char* Pb = lds + P_OFF;                  // block-shared P [64q][64B row]

  // per-lane global byte offsets for the 3 K gload_lds per wave
  int koffB[3];
#pragma unroll
  for (int i = 0; i < 3; ++i){
    int L = (w * 3 + i) * 64 + lane;              // granule 0..767
    int m   = L / 24;
    int pos = L - m * 24;
    int cc  = (pos >> 3) * 8 + ((pos & 7) ^ (m & 7));
    koffB[i] = m * C_ + cc * 16;
  }
  // per-lane global element offsets for the 6 V gload_lds per wave
  int voff[6];
#pragma unroll
  for (int i = 0; i < 6; ++i){
    int chunk = (w * 6 + i) * 64 + lane;          // 0..1535
    int line = chunk >> 3;
    int u    = (chunk & 7) ^ (line & 7);
    voff[i]  = (line * 2 + (u >> 2)) * N_ + (u & 3) * 8;
  }

  // P offsets: row q (64B), phys granule = logical ^ s(q), s(q) = (l15>>1)&3
  const int s_l  = (l15 >> 1) & 3;
  const int p_w0 = (qw*32      + l15) * 64 + (((2*mw + (lg >> 1)) ^ s_l) << 4) + (lg & 1) * 8;
  const int p_w1 = (qw*32 + 16 + l15) * 64 + (((2*mw + (lg >> 1)) ^ s_l) << 4) + (lg & 1) * 8;
  const int p_rc = ((lg ^ s_l) << 4) + l15 * 64;   // + qf2*1024

  auto stageK = [&](int t, int buf){
    const unsigned char* kb = kmat + (size_t)t * 32 * C_;
    char* kdst = lds + (buf ? KB1_ : KB0_) + w * 3072;
#pragma unroll
    for (int i = 0; i < 3; ++i) gload_lds16(kb + koffB[i], kdst + i * 1024);
  };
  auto stageV = [&](int t){
    const unsigned short* vb = vmat + t * 32;
    char* vdst = lds + VB_ + w * 6144;
#pragma unroll
    for (int i = 0; i < 6; ++i) gload_lds16(vb + voff[i], vdst + i * 1024);
  };

  // prologue: K0->kb0, V0->vb, K1->kb1; wait K0 (V0 + K1 stay in flight)
  stageK(0, 0);
  stageV(0);
  stageK(1, 1);
  asm volatile("s_waitcnt vmcnt(9)" ::: "memory");
  __builtin_amdgcn_sched_barrier(0);
  __builtin_amdgcn_s_barrier();
  __builtin_amdgcn_sched_barrier(0);

  const int krow = (mw * 16 + l15);        // K LDS row this lane reads
  for (int mt = 0; mt < 50; ++mt){
    int cur = mt & 1;
    const char* kbR = lds + (cur ? KB1_ : KB0_);

    // ---- QK^T fp8 (swapped): sim[mw-tile][qw 32q], 12 a-loads, 24 MFMAs
    f32x4 s0 = {0.f,0.f,0.f,0.f}, s1 = {0.f,0.f,0.f,0.f};
    __builtin_amdgcn_s_setprio(1);
#pragma unroll
    for (int ks = 0; ks < 12; ++ks){
      int lc  = 2 * ks + (lg >> 1);
      int off = ((lc >> 3) * 8 + ((lc & 7) ^ (krow & 7))) * 16 + (lg & 1) * 8;
      i64t a = *(const i64t*)(kbR + krow * 384 + off);
      s0 = __builtin_amdgcn_mfma_f32_16x16x32_fp8_fp8(a, qreg[0][ks], s0, 0, 0, 0);
      s1 = __builtin_amdgcn_mfma_f32_16x16x32_fp8_fp8(a, qreg[1][ks], s1, 0, 0, 0);
    }
    __builtin_amdgcn_s_setprio(0);

    // ---- P = exp2((sim-1)*log2e/tau), quantize bf16, accumulate l per q
    ushort4 pw0, pw1;
    {
      __bf16 h;
      float l0 = 0.f, l1 = 0.f;
      h = (__bf16)exp2f((s0[0]-1.f)*sc); l0 += (float)h; pw0.x = __builtin_bit_cast(unsigned short, h);
      h = (__bf16)exp2f((s0[1]-1.f)*sc); l0 += (float)h; pw0.y = __builtin_bit_cast(unsigned short, h);
      h = (__bf16)exp2f((s0[2]-1.f)*sc); l0 += (float)h; pw0.z = __builtin_bit_cast(unsigned short, h);
      h = (__bf16)exp2f((s0[3]-1.f)*sc); l0 += (float)h; pw0.w = __builtin_bit_cast(unsigned short, h);
      h = (__bf16)exp2f((s1[0]-1.f)*sc); l1 += (float)h; pw1.x = __builtin_bit_cast(unsigned short, h);
      h = (__bf16)exp2f((s1[1]-1.f)*sc); l1 += (float)h; pw1.y = __builtin_bit_cast(unsigned short, h);
      h = (__bf16)exp2f((s1[2]-1.f)*sc); l1 += (float)h; pw1.z = __builtin_bit_cast(unsigned short, h);
      h = (__bf16)exp2f((s1[3]-1.f)*sc); l1 += (float)h; pw1.w = __builtin_bit_cast(unsigned short, h);
      lsum0 += l0; lsum1 += l1;
    }
    *(ushort4*)(Pb + p_w0) = pw0;   // q = qw*32+l15,    m = mw*16+lg*4..+3
    *(ushort4*)(Pb + p_w1) = pw1;   // q = qw*32+16+l15, m = mw*16+lg*4..+3
    // retire P-writes + {K(t+1), V(t)} (both had >= half-iter of flight)
    asm volatile("s_waitcnt lgkmcnt(0) vmcnt(0)" ::: "memory");
    __builtin_amdgcn_sched_barrier(0);
    __builtin_amdgcn_s_barrier();          // bar1: P visible; K(t) read; V(t) in
    __builtin_amdgcn_sched_barrier(0);

    // ---- stage K(t+2) into kb[cur] (its readers finished at bar1)
    int tk = (mt + 2 < 50) ? mt + 2 : mt;
    stageK(tk, cur);
    __builtin_amdgcn_sched_barrier(0);

    // ---- PV c-split: O[64q][w*96..+96] += P * V (P + V from LDS)
    bf16x8 pa[4];
#pragma unroll
    for (int qf2 = 0; qf2 < 4; ++qf2)
      pa[qf2] = *(const bf16x8*)(Pb + qf2 * 1024 + p_rc);  // P[qf2*16+l15][lg*8..+7]
    __builtin_amdgcn_s_setprio(1);
#pragma unroll
    for (int cf = 0; cf < 6; ++cf){
      int c  = w * 96 + cf * 16 + l15;
      int vo = (c >> 1) * 128 + (((lg | ((c & 1) << 2)) ^ ((c >> 1) & 7)) << 4);
      bf16x8 vf = *(const bf16x8*)(lds + VB_ + vo);
#pragma unroll
      for (int qf2 = 0; qf2 < 4; ++qf2)
        o[qf2][cf] = __builtin_amdgcn_mfma_f32_16x16x32_bf16(pa[qf2], vf, o[qf2][cf], 0, 0, 0);
    }
    __builtin_amdgcn_s_setprio(0);

    __builtin_amdgcn_sched_barrier(0);
    __builtin_amdgcn_s_barrier();          // bar2: V(t)/P(t) fully consumed
    __builtin_amdgcn_sched_barrier(0);

    // ---- stage V(t+1) into the (now free) single V buffer; flies thru QK(t+1)
    int tv = (mt + 1 < 50) ? mt + 1 : 49;
    stageV(tv);
    __builtin_amdgcn_sched_barrier(0);
  }

  // ---- finalize: l per q = sum over both m-half waves
  lsum0 += __shfl_xor(lsum0, 16, 64);
  lsum0 += __shfl_xor(lsum0, 32, 64);
  lsum1 += __shfl_xor(lsum1, 16, 64);
  lsum1 += __shfl_xor(lsum1, 32, 64);
  __syncthreads();                         // drains dead prefetches; loop done
  float* lsh = (float*)lds;                // [2 mw][64 q]
  if (lg == 0){
    lsh[mw * 64 + qw * 32 + l15]      = lsum0;
    lsh[mw * 64 + qw * 32 + 16 + l15] = lsum1;
  }
  __syncthreads();
  float invl[4][4];
#pragma unroll
  for (int qf2 = 0; qf2 < 4; ++qf2)
#pragma unroll
    for (int rg = 0; rg < 4; ++rg){
      int q = qf2 * 16 + lg * 4 + rg;
      invl[qf2][rg] = 1.f / (lsh[q] + lsh[64 + q]);
    }

  int qbase = qt * 64;
  unsigned short* op = Or + ((size_t)rb * N_ + qbase) * C_ + w * 96 + l15;
#pragma unroll
  for (int qf2 = 0; qf2 < 4; ++qf2){
#pragma unroll
    for (int cf = 0; cf < 6; ++cf){
#pragma unroll
      for (int rg = 0; rg < 4; ++rg){
        int q = qf2 * 16 + lg * 4 + rg;
        op[(size_t)q * C_ + cf * 16] = f2bf(o[qf2][cf][rg] * invl[qf2][rg]);
      }
    }
  }
}

// --------------------------------------------------------------- combine ----
// out[b][c][n] = feats + mask*alpha*(sum_r Or/4 - feats); transpose [n][c]->[c][n]
__global__ void combine_kernel(const unsigned short* __restrict__ Or,
                               const float* __restrict__ feats,
                               const float* __restrict__ maskp,
                               const float* __restrict__ alpha_raw,
                               float* __restrict__ out){
  int nt = blockIdx.x, ct = blockIdx.y, b = blockIdx.z;
  __shared__ float tile[64][65];
  float alpha = 1.f / (1.f + expf(-alpha_raw[0]));
  int t = threadIdx.x;
#pragma unroll
  for (int i = 0; i < 4; ++i){
    int chunk = t + 256 * i;
    int nr = chunk >> 4, c4 = chunk & 15;
    size_t base = ((size_t)b * N_ + nt * 64 + nr) * C_ + ct * 64 + c4 * 4;
    float4 s = {0.f,0.f,0.f,0.f};
#pragma unroll
    for (int r = 0; r < 4; ++r){
      ushort4 v = *(const ushort4*)(Or + (size_t)r * B_ * N_ * C_ + base);
      s.x += bf2f(v.x); s.y += bf2f(v.y); s.z += bf2f(v.z); s.w += bf2f(v.w);
    }
    tile[nr][c4*4+0] = s.x; tile[nr][c4*4+1] = s.y;
    tile[nr][c4*4+2] = s.z; tile[nr][c4*4+3] = s.w;
  }
  __syncthreads();
#pragma unroll
  for (int i = 0; i < 4; ++i){
    int chunk = t + 256 * i;
    int cr = chunk >> 4, n4 = chunk & 15;
    size_t fb = ((size_t)b * C_ + ct * 64 + cr) * N_ + nt * 64 + n4 * 4;
    float4 f  = *(const float4*)(feats + fb);
    float4 mk = *(const float4*)(maskp + (size_t)b * N_ + nt * 64 + n4 * 4);
    float4 ov;
    ov.x = f.x + mk.x * alpha * (tile[n4*4+0][cr] * 0.25f - f.x);
    ov.y = f.y + mk.y * alpha * (tile[n4*4+1][cr] * 0.25f - f.y);
    ov.z = f.z + mk.z * alpha * (tile[n4*4+2][cr] * 0.25f - f.z);
    ov.w = f.w + mk.w * alpha * (tile[n4*4+3][cr] * 0.25f - f.w);
    *(float4*)(out + fb) = ov;
  }
}

// ws-too-small sentinel: recognizable absmax ~1e6
__global__ void poison_kernel(float* out, int n){
  int i = blockIdx.x * 256 + threadIdx.x;
  if (i < n) out[i] = 1.0e6f;
}

extern "C" void kernel_launch(void* const* d_in, const int* in_sizes, int n_in,
                              void* d_out, int out_size, void* d_ws, size_t ws_size,
                              hipStream_t stream){
  const float* feats     = (const float*)d_in[0];
  const float* refs      = (const float*)d_in[1];
  const float* sopm      = (const float*)d_in[2];
  const float* log_tau   = (const float*)d_in[3];
  const float* alpha_raw = (const float*)d_in[4];
  float* out = (float*)d_out;

  const size_t SZ_MASK = (size_t)B_ * N_ * 4;              //    51,200
  const size_t SZ_QB   = (size_t)B_ * N_ * C_;             // 4,915,200 (fp8)
  const size_t SZ_KB   = (size_t)R_ * B_ * N_ * C_;        // 19,660,800 (fp8)
  const size_t SZ_VB   = (size_t)R_ * B_ * N_ * C_ * 2;    // 39,321,600 (bf16)
  const size_t SZ_OR   = (size_t)R_ * B_ * N_ * C_ * 2;    // 39,321,600 (bf16)
  const size_t need = SZ_MASK + SZ_QB + SZ_KB + SZ_VB + SZ_OR;

  if (ws_size < need){
    poison_kernel<<<(out_size + 255) / 256, 256, 0, stream>>>(out, out_size);
    return;
  }
  char* ws = (char*)d_ws;
  float*          maskp = (float*)ws;
  unsigned char*  Qb    = (unsigned char*)(ws + SZ_MASK);
  unsigned char*  Kb    = (unsigned char*)(ws + SZ_MASK + SZ_QB);
  unsigned short* Vb    = (unsigned short*)(ws + SZ_MASK + SZ_QB + SZ_KB);
  unsigned short* Or    = (unsigned short*)(ws + SZ_MASK + SZ_QB + SZ_KB + SZ_VB);

  mask_kernel   <<<50, 256, 0, stream>>>(sopm, maskp);
  prep_kernel   <<<dim3(25, 40), 256, 0, stream>>>(feats, refs, Qb, Kb, Vb);
  attn_kernel   <<<800, 256, 0, stream>>>(Qb, Kb, Vb, log_tau, Or);
  combine_kernel<<<dim3(25, 6, 8), 256, 0, stream>>>(Or, feats, maskp, alpha_raw, out);
}

// Round 17
// 198.867 us; speedup vs baseline: 1.0940x; 1.0175x over previous
//
#include <hip/hip_runtime.h>
#include <stdint.h>

// Problem constants (fixed by reference)
#define B_  8
#define C_  384
#define N_  1600
#define R_  4
#define S_  160
#define HW_ 40

typedef float  f32x4  __attribute__((ext_vector_type(4)));
typedef __bf16 bf16x8 __attribute__((ext_vector_type(8)));
typedef long long i64t;

__device__ __forceinline__ unsigned short f2bf(float x){
  __bf16 h = (__bf16)x;                         // RNE
  return __builtin_bit_cast(unsigned short, h);
}
__device__ __forceinline__ float bf2f(unsigned short u){
  return __builtin_bit_cast(float, (uint32_t)u << 16);
}
// pack 4 floats -> 4 OCP e4m3 bytes (v_cvt_pk_fp8_f32 on gfx950 emits OCP)
__device__ __forceinline__ uint32_t pk_fp8x4(float a, float b, float c, float d){
  int lo = __builtin_amdgcn_cvt_pk_fp8_f32(a, b, 0, false);
  int hi = __builtin_amdgcn_cvt_pk_fp8_f32(c, d, 0, false);
  return (uint32_t)(lo & 0xffff) | ((uint32_t)hi << 16);
}

// async global->LDS, 16B per lane; LDS dest is wave-uniform base + lane*16
__device__ __forceinline__ void gload_lds16(const void* g, void* l){
  __builtin_amdgcn_global_load_lds(
      (const __attribute__((address_space(1))) uint32_t*)g,
      (__attribute__((address_space(3))) uint32_t*)l, 16, 0, 0);
}

// ------------------------------------------- fused norm + transpose/convert ----
// One block per (nt, mat): reads the 64n x 384c f32 tile ONCE, writes V bf16
// inline, computes row norms from registers+LDS partials, then emits
// Q/K fp8 [n][c] from the bf16 LDS tile.
__global__ void prep_kernel(const float* __restrict__ feats,
                            const float* __restrict__ refs,
                            unsigned char* __restrict__ Qb,
                            unsigned char* __restrict__ Kb,
                            unsigned short* __restrict__ Vb){
  int nt = blockIdx.x, mat = blockIdx.y;
  __shared__ unsigned short tile[64][386];   // [n][c] bf16; 772B rows (odd dwords)
  __shared__ float ssp[64][17];              // per-n partial sums (16 producers)
  __shared__ float inv_sh[64];
  int t = threadIdx.x;
  bool isref = (mat >= B_);
  const float* src = isref ? refs  + (size_t)(mat - B_) * C_ * N_
                           : feats + (size_t)mat * C_ * N_;
  int n4  = t & 15;        // owns n = n4*4 .. +3 (fixed per thread)
  int crb = t >> 4;        // c-row base 0..15
  float ss4[4] = {0.f, 0.f, 0.f, 0.f};
#pragma unroll
  for (int ct = 0; ct < 6; ++ct){
#pragma unroll
    for (int i = 0; i < 4; ++i){
      int c = ct * 64 + crb + 16 * i;
      size_t off = (size_t)c * N_ + nt * 64 + n4 * 4;
      float4 v = *(const float4*)(src + off);
      ushort4 o;
      o.x = f2bf(v.x); o.y = f2bf(v.y); o.z = f2bf(v.z); o.w = f2bf(v.w);
      if (isref){
        unsigned short* vdst = Vb + (size_t)(mat - B_) * C_ * N_;
        *(ushort4*)(vdst + off) = o;       // V = raw bf16, same [c][n] layout
      }
      tile[n4*4+0][c] = o.x;
      tile[n4*4+1][c] = o.y;
      tile[n4*4+2][c] = o.z;
      tile[n4*4+3][c] = o.w;
      ss4[0] += v.x * v.x;  ss4[1] += v.y * v.y;
      ss4[2] += v.z * v.z;  ss4[3] += v.w * v.w;
    }
  }
#pragma unroll
  for (int j = 0; j < 4; ++j) ssp[n4*4+j][crb] = ss4[j];
  __syncthreads();
  if (t < 64){
    float s = 0.f;
#pragma unroll
    for (int p = 0; p < 16; ++p) s += ssp[t][p];
    inv_sh[t] = 1.f / fmaxf(sqrtf(s), 1e-12f);
  }
  __syncthreads();
  unsigned char* dst = isref ? Kb + (size_t)(mat - B_) * N_ * C_
                             : Qb + (size_t)mat * N_ * C_;
#pragma unroll
  for (int i = 0; i < 4; ++i){
    int nr = (t >> 4) + 16 * i;
    float iv = inv_sh[nr];
    unsigned char* drow = dst + (size_t)(nt * 64 + nr) * C_;
#pragma unroll
    for (int ct = 0; ct < 6; ++ct){
      int c0 = ct * 64 + (t & 15) * 4;
      uint32_t a0 = *(const uint32_t*)(&tile[nr][c0]);      // bf16 pair c0,c0+1
      uint32_t a1 = *(const uint32_t*)(&tile[nr][c0 + 2]);  // bf16 pair c0+2,+3
      uint32_t pk = pk_fp8x4(bf2f((unsigned short)(a0 & 0xffff)) * iv,
                             bf2f((unsigned short)(a0 >> 16))    * iv,
                             bf2f((unsigned short)(a1 & 0xffff)) * iv,
                             bf2f((unsigned short)(a1 >> 16))    * iv);
      *(uint32_t*)(drow + c0) = pk;
    }
  }
}

// ------------------------------------------------------------------ mask ----
__global__ void mask_kernel(const float* __restrict__ sopm,
                            float* __restrict__ maskp){
  int gid = blockIdx.x * 256 + threadIdx.x;       // 12800
  int b = gid / N_, n = gid - b * N_;
  int oy = n / HW_, ox = n - oy * HW_;
  const float* sp = sopm + (size_t)b * S_ * S_;
  float cy = oy * 4 + 1.5f, cx = ox * 4 + 1.5f;
  int y0 = 4*oy - 2; if (y0 < 0) y0 = 0;
  int y1 = 4*oy + 5; if (y1 > S_-1) y1 = S_-1;
  int x0 = 4*ox - 2; if (x0 < 0) x0 = 0;
  int x1 = 4*ox + 5; if (x1 > S_-1) x1 = S_-1;
  float wsy = 0.f, wsx = 0.f;
  for (int j = y0; j <= y1; ++j) wsy += 1.f - fabsf(j - cy) * 0.25f;
  for (int j = x0; j <= x1; ++j) wsx += 1.f - fabsf(j - cx) * 0.25f;
  float acc = 0.f;
  for (int jy = y0; jy <= y1; ++jy){
    float wy = 1.f - fabsf(jy - cy) * 0.25f;
    float rs = 0.f;
    for (int jx = x0; jx <= x1; ++jx)
      rs += (1.f - fabsf(jx - cx) * 0.25f) * sp[jy * S_ + jx];
    acc += wy * rs;
  }
  float val = acc / (wsy * wsx);
  maskp[gid] = (val > 0.3f) ? 1.f : 0.f;
}

// ------------------------------------------------------------- attention ----
// T15 phase-shifted pipeline variant of the proven R10/R13 kernel.
// grid 800 = (r*B+b)*25 + qtile (XCD-swizzled). Block: 4 waves.
// QK 2x2 wave-split (sim[mw*16..+16][qw*32..+32]); P block-shared (single buf);
// PV c-split (c=w*96..+96); K double-buffered; V single-buffered.
// Pipeline: QK(0) in prologue; per iter t:
//  phase A: softmax(t) on s-regs from the PREVIOUS phase B (no exposed MFMA
//           latency), P-write | lgkm0+vmcnt0 | bar1
//  phase B: stageK(t+2); pa-read; {QK(t+1) + PV(t)} as ONE 48-MFMA burst
//           (independent accumulators) | bar2 | stageV(t+1)
// Buffer safety: P(t) overwrite needs PV(t-1) done -> bar2(t-1). kb[cur]
// overwrite needs QK(t) done -> phase B(t-1) ended at bar2(t-1). V overwrite
// needs PV(t) done -> bar2(t). All full vmcnt drains -> guards may skip stages.
#define KB0_   0
#define KB1_   12288
#define VB_    24576
#define P_OFF  49152
#define LDS_SZ 53248

__global__ __launch_bounds__(256, 2) void attn_kernel(
    const unsigned char* __restrict__ Qb,
    const unsigned char* __restrict__ Kb,
    const unsigned short* __restrict__ Vb,
    const float* __restrict__ log_tau,
    unsigned short* __restrict__ Or)
{
  __shared__ __align__(16) char lds[LDS_SZ];
  int wg   = blockIdx.x;
  int orig = (wg & 7) * 100 + (wg >> 3);   // XCD-contiguous chunks (800 = 8*100)
  int qt   = orig % 25;
  int rb   = orig / 25;                    // r*B + b
  int b    = rb & 7;
  int tid  = threadIdx.x;
  int lane = tid & 63;
  int w    = tid >> 6;
  int mw   = w >> 1;                       // m-half for QK
  int qw   = w & 1;                        // q-half for QK
  int l15  = lane & 15;
  int lg   = lane >> 4;

  float tau = expf(log_tau[0]);
  tau = fminf(fmaxf(tau, 0.005f), 0.1f);
  float sc = 1.4426950408889634f / tau;    // log2(e)/tau

  // Q fp8 fragments: 32 q rows (2 q-tiles) in regs (48 VGPR)
  i64t qreg[2][12];
#pragma unroll
  for (int qt2 = 0; qt2 < 2; ++qt2){
    const unsigned char* qp = Qb +
        ((size_t)b * N_ + qt * 64 + qw * 32 + qt2 * 16 + l15) * C_ + lg * 8;
#pragma unroll
    for (int ks = 0; ks < 12; ++ks)
      qreg[qt2][ks] = *(const i64t*)(qp + ks * 32);
  }

  // O accumulator: [qf2 0..3][cf 0..5] -> O[qf2*16 + lg*4 + rg][w*96 + cf*16 + l15]
  f32x4 o[4][6];
#pragma unroll
  for (int i = 0; i < 4; ++i)
#pragma unroll
    for (int j = 0; j < 6; ++j) o[i][j] = (f32x4){0.f,0.f,0.f,0.f};
  float lsum0 = 0.f, lsum1 = 0.f;          // l for q = qw*32 + {l15, 16+l15}

  const unsigned char*  kmat = Kb + (size_t)rb * N_ * C_;
  const unsigned short* vmat = Vb + (size_t)rb * C_ * N_;
  char* Pb = lds + P_OFF;                  // block-shared P [64q][64B row]

  // per-lane global byte offsets for the 3 K gload_lds per wave
  int koffB[3];
#pragma unroll
  for (int i = 0; i < 3; ++i){
    int L = (w * 3 + i) * 64 + lane;              // granule 0..767
    int m   = L / 24;
    int pos = L - m * 24;
    int cc  = (pos >> 3) * 8 + ((pos & 7) ^ (m & 7));
    koffB[i] = m * C_ + cc * 16;
  }
  // per-lane global element offsets for the 6 V gload_lds per wave
  int voff[6];
#pragma unroll
  for (int i = 0; i < 6; ++i){
    int chunk = (w * 6 + i) * 64 + lane;          // 0..1535
    int line = chunk >> 3;
    int u    = (chunk & 7) ^ (line & 7);
    voff[i]  = (line * 2 + (u >> 2)) * N_ + (u & 3) * 8;
  }

  // P offsets: row q (64B), phys granule = logical ^ s(q), s(q) = (l15>>1)&3
  const int s_l  = (l15 >> 1) & 3;
  const int p_w0 = (qw*32      + l15) * 64 + (((2*mw + (lg >> 1)) ^ s_l) << 4) + (lg & 1) * 8;
  const int p_w1 = (qw*32 + 16 + l15) * 64 + (((2*mw + (lg >> 1)) ^ s_l) << 4) + (lg & 1) * 8;
  const int p_rc = ((lg ^ s_l) << 4) + l15 * 64;   // + qf2*1024

  auto stageK = [&](int t, int buf){
    const unsigned char* kb = kmat + (size_t)t * 32 * C_;
    char* kdst = lds + (buf ? KB1_ : KB0_) + w * 3072;
#pragma unroll
    for (int i = 0; i < 3; ++i) gload_lds16(kb + koffB[i], kdst + i * 1024);
  };
  auto stageV = [&](int t){
    const unsigned short* vb = vmat + t * 32;
    char* vdst = lds + VB_ + w * 6144;
#pragma unroll
    for (int i = 0; i < 6; ++i) gload_lds16(vb + voff[i], vdst + i * 1024);
  };
  const int krow = (mw * 16 + l15);        // K LDS row this lane reads
  auto computeQK = [&](const char* kbR, f32x4& a0acc, f32x4& a1acc){
#pragma unroll
    for (int ks = 0; ks < 12; ++ks){
      int lc  = 2 * ks + (lg >> 1);
      int off = ((lc >> 3) * 8 + ((lc & 7) ^ (krow & 7))) * 16 + (lg & 1) * 8;
      i64t a = *(const i64t*)(kbR + krow * 384 + off);
      a0acc = __builtin_amdgcn_mfma_f32_16x16x32_fp8_fp8(a, qreg[0][ks], a0acc, 0, 0, 0);
      a1acc = __builtin_amdgcn_mfma_f32_16x16x32_fp8_fp8(a, qreg[1][ks], a1acc, 0, 0, 0);
    }
  };

  // prologue: K0->kb0, V0->vb, K1->kb1; wait K0 (V0 + K1 stay in flight);
  // then QK(0) so the loop starts with its softmax.
  stageK(0, 0);
  stageV(0);
  stageK(1, 1);
  asm volatile("s_waitcnt vmcnt(9)" ::: "memory");
  __builtin_amdgcn_sched_barrier(0);
  __builtin_amdgcn_s_barrier();
  __builtin_amdgcn_sched_barrier(0);

  f32x4 s0 = {0.f,0.f,0.f,0.f}, s1 = {0.f,0.f,0.f,0.f};
  computeQK(lds + KB0_, s0, s1);           // QK(0)

  for (int mt = 0; mt < 50; ++mt){
    int cur = mt & 1;

    // ---- phase A: softmax(mt) on s-regs from previous phase; P-write
    ushort4 pw0, pw1;
    {
      __bf16 h;
      float l0 = 0.f, l1 = 0.f;
      h = (__bf16)exp2f((s0[0]-1.f)*sc); l0 += (float)h; pw0.x = __builtin_bit_cast(unsigned short, h);
      h = (__bf16)exp2f((s0[1]-1.f)*sc); l0 += (float)h; pw0.y = __builtin_bit_cast(unsigned short, h);
      h = (__bf16)exp2f((s0[2]-1.f)*sc); l0 += (float)h; pw0.z = __builtin_bit_cast(unsigned short, h);
      h = (__bf16)exp2f((s0[3]-1.f)*sc); l0 += (float)h; pw0.w = __builtin_bit_cast(unsigned short, h);
      h = (__bf16)exp2f((s1[0]-1.f)*sc); l1 += (float)h; pw1.x = __builtin_bit_cast(unsigned short, h);
      h = (__bf16)exp2f((s1[1]-1.f)*sc); l1 += (float)h; pw1.y = __builtin_bit_cast(unsigned short, h);
      h = (__bf16)exp2f((s1[2]-1.f)*sc); l1 += (float)h; pw1.z = __builtin_bit_cast(unsigned short, h);
      h = (__bf16)exp2f((s1[3]-1.f)*sc); l1 += (float)h; pw1.w = __builtin_bit_cast(unsigned short, h);
      lsum0 += l0; lsum1 += l1;
    }
    *(ushort4*)(Pb + p_w0) = pw0;   // q = qw*32+l15,    m = mw*16+lg*4..+3
    *(ushort4*)(Pb + p_w1) = pw1;   // q = qw*32+16+l15, m = mw*16+lg*4..+3
    // retire P-writes + {K(mt+1), V(mt)} (both in flight >= one full phase)
    asm volatile("s_waitcnt lgkmcnt(0) vmcnt(0)" ::: "memory");
    __builtin_amdgcn_sched_barrier(0);
    __builtin_amdgcn_s_barrier();          // bar1: P visible; K(mt+1), V(mt) in
    __builtin_amdgcn_sched_barrier(0);

    // ---- stage K(mt+2) into kb[cur] (QK(mt) readers done at bar2(mt-1))
    if (mt + 2 < 50) stageK(mt + 2, cur);
    __builtin_amdgcn_sched_barrier(0);

    // ---- phase B: one MFMA burst = QK(mt+1) + PV(mt) (independent accs)
    bf16x8 pa[4];
#pragma unroll
    for (int qf2 = 0; qf2 < 4; ++qf2)
      pa[qf2] = *(const bf16x8*)(Pb + qf2 * 1024 + p_rc);  // P[qf2*16+l15][lg*8..+7]
    __builtin_amdgcn_s_setprio(1);
    if (mt + 1 < 50){
      s0 = (f32x4){0.f,0.f,0.f,0.f};
      s1 = (f32x4){0.f,0.f,0.f,0.f};
      computeQK(lds + ((cur ^ 1) ? KB1_ : KB0_), s0, s1);  // QK(mt+1)
    }
#pragma unroll
    for (int cf = 0; cf < 6; ++cf){
      int c  = w * 96 + cf * 16 + l15;
      int vo = (c >> 1) * 128 + (((lg | ((c & 1) << 2)) ^ ((c >> 1) & 7)) << 4);
      bf16x8 vf = *(const bf16x8*)(lds + VB_ + vo);
#pragma unroll
      for (int qf2 = 0; qf2 < 4; ++qf2)
        o[qf2][cf] = __builtin_amdgcn_mfma_f32_16x16x32_bf16(pa[qf2], vf, o[qf2][cf], 0, 0, 0);
    }
    __builtin_amdgcn_s_setprio(0);

    __builtin_amdgcn_sched_barrier(0);
    __builtin_amdgcn_s_barrier();          // bar2: V(mt)/P(mt)/K(mt+1) consumed
    __builtin_amdgcn_sched_barrier(0);

    // ---- stage V(mt+1) into the single V buffer; flies through phase A(mt+1)
    if (mt + 1 < 50) stageV(mt + 1);
    __builtin_amdgcn_sched_barrier(0);
  }

  // ---- finalize: l per q = sum over both m-half waves
  lsum0 += __shfl_xor(lsum0, 16, 64);
  lsum0 += __shfl_xor(lsum0, 32, 64);
  lsum1 += __shfl_xor(lsum1, 16, 64);
  lsum1 += __shfl_xor(lsum1, 32, 64);
  __syncthreads();                         // loop done; LDS reusable
  float* lsh = (float*)lds;                // [2 mw][64 q]
  if (lg == 0){
    lsh[mw * 64 + qw * 32 + l15]      = lsum0;
    lsh[mw * 64 + qw * 32 + 16 + l15] = lsum1;
  }
  __syncthreads();
  float invl[4][4];
#pragma unroll
  for (int qf2 = 0; qf2 < 4; ++qf2)
#pragma unroll
    for (int rg = 0; rg < 4; ++rg){
      int q = qf2 * 16 + lg * 4 + rg;
      invl[qf2][rg] = 1.f / (lsh[q] + lsh[64 + q]);
    }

  int qbase = qt * 64;
  unsigned short* op = Or + ((size_t)rb * N_ + qbase) * C_ + w * 96 + l15;
#pragma unroll
  for (int qf2 = 0; qf2 < 4; ++qf2){
#pragma unroll
    for (int cf = 0; cf < 6; ++cf){
#pragma unroll
      for (int rg = 0; rg < 4; ++rg){
        int q = qf2 * 16 + lg * 4 + rg;
        op[(size_t)q * C_ + cf * 16] = f2bf(o[qf2][cf][rg] * invl[qf2][rg]);
      }
    }
  }
}

// --------------------------------------------------------------- combine ----
// out[b][c][n] = feats + mask*alpha*(sum_r Or/4 - feats); transpose [n][c]->[c][n]
__global__ void combine_kernel(const unsigned short* __restrict__ Or,
                               const float* __restrict__ feats,
                               const float* __restrict__ maskp,
                               const float* __restrict__ alpha_raw,
                               float* __restrict__ out){
  int nt = blockIdx.x, ct = blockIdx.y, b = blockIdx.z;
  __shared__ float tile[64][65];
  float alpha = 1.f / (1.f + expf(-alpha_raw[0]));
  int t = threadIdx.x;
#pragma unroll
  for (int i = 0; i < 4; ++i){
    int chunk = t + 256 * i;
    int nr = chunk >> 4, c4 = chunk & 15;
    size_t base = ((size_t)b * N_ + nt * 64 + nr) * C_ + ct * 64 + c4 * 4;
    float4 s = {0.f,0.f,0.f,0.f};
#pragma unroll
    for (int r = 0; r < 4; ++r){
      ushort4 v = *(const ushort4*)(Or + (size_t)r * B_ * N_ * C_ + base);
      s.x += bf2f(v.x); s.y += bf2f(v.y); s.z += bf2f(v.z); s.w += bf2f(v.w);
    }
    tile[nr][c4*4+0] = s.x; tile[nr][c4*4+1] = s.y;
    tile[nr][c4*4+2] = s.z; tile[nr][c4*4+3] = s.w;
  }
  __syncthreads();
#pragma unroll
  for (int i = 0; i < 4; ++i){
    int chunk = t + 256 * i;
    int cr = chunk >> 4, n4 = chunk & 15;
    size_t fb = ((size_t)b * C_ + ct * 64 + cr) * N_ + nt * 64 + n4 * 4;
    float4 f  = *(const float4*)(feats + fb);
    float4 mk = *(const float4*)(maskp + (size_t)b * N_ + nt * 64 + n4 * 4);
    float4 ov;
    ov.x = f.x + mk.x * alpha * (tile[n4*4+0][cr] * 0.25f - f.x);
    ov.y = f.y + mk.y * alpha * (tile[n4*4+1][cr] * 0.25f - f.y);
    ov.z = f.z + mk.z * alpha * (tile[n4*4+2][cr] * 0.25f - f.z);
    ov.w = f.w + mk.w * alpha * (tile[n4*4+3][cr] * 0.25f - f.w);
    *(float4*)(out + fb) = ov;
  }
}

// ws-too-small sentinel: recognizable absmax ~1e6
__global__ void poison_kernel(float* out, int n){
  int i = blockIdx.x * 256 + threadIdx.x;
  if (i < n) out[i] = 1.0e6f;
}

extern "C" void kernel_launch(void* const* d_in, const int* in_sizes, int n_in,
                              void* d_out, int out_size, void* d_ws, size_t ws_size,
                              hipStream_t stream){
  const float* feats     = (const float*)d_in[0];
  const float* refs      = (const float*)d_in[1];
  const float* sopm      = (const float*)d_in[2];
  const float* log_tau   = (const float*)d_in[3];
  const float* alpha_raw = (const float*)d_in[4];
  float* out = (float*)d_out;

  const size_t SZ_MASK = (size_t)B_ * N_ * 4;              //    51,200
  const size_t SZ_QB   = (size_t)B_ * N_ * C_;             // 4,915,200 (fp8)
  const size_t SZ_KB   = (size_t)R_ * B_ * N_ * C_;        // 19,660,800 (fp8)
  const size_t SZ_VB   = (size_t)R_ * B_ * N_ * C_ * 2;    // 39,321,600 (bf16)
  const size_t SZ_OR   = (size_t)R_ * B_ * N_ * C_ * 2;    // 39,321,600 (bf16)
  const size_t need = SZ_MASK + SZ_QB + SZ_KB + SZ_VB + SZ_OR;

  if (ws_size < need){
    poison_kernel<<<(out_size + 255) / 256, 256, 0, stream>>>(out, out_size);
    return;
  }
  char* ws = (char*)d_ws;
  float*          maskp = (float*)ws;
  unsigned char*  Qb    = (unsigned char*)(ws + SZ_MASK);
  unsigned char*  Kb    = (unsigned char*)(ws + SZ_MASK + SZ_QB);
  unsigned short* Vb    = (unsigned short*)(ws + SZ_MASK + SZ_QB + SZ_KB);
  unsigned short* Or    = (unsigned short*)(ws + SZ_MASK + SZ_QB + SZ_KB + SZ_VB);

  mask_kernel   <<<50, 256, 0, stream>>>(sopm, maskp);
  prep_kernel   <<<dim3(25, 40), 256, 0, stream>>>(feats, refs, Qb, Kb, Vb);
  attn_kernel   <<<800, 256, 0, stream>>>(Qb, Kb, Vb, log_tau, Or);
  combine_kernel<<<dim3(25, 6, 8), 256, 0, stream>>>(Or, feats, maskp, alpha_raw, out);
}

// Round 18
// 194.389 us; speedup vs baseline: 1.1192x; 1.0230x over previous
//
#include <hip/hip_runtime.h>
#include <stdint.h>

// Problem constants (fixed by reference)
#define B_  8
#define C_  384
#define N_  1600
#define R_  4
#define S_  160
#define HW_ 40

typedef float  f32x4  __attribute__((ext_vector_type(4)));
typedef __bf16 bf16x8 __attribute__((ext_vector_type(8)));
typedef long long i64t;

__device__ __forceinline__ unsigned short f2bf(float x){
  __bf16 h = (__bf16)x;                         // RNE
  return __builtin_bit_cast(unsigned short, h);
}
__device__ __forceinline__ float bf2f(unsigned short u){
  return __builtin_bit_cast(float, (uint32_t)u << 16);
}
// pack 4 floats -> 4 OCP e4m3 bytes (v_cvt_pk_fp8_f32 on gfx950 emits OCP)
__device__ __forceinline__ uint32_t pk_fp8x4(float a, float b, float c, float d){
  int lo = __builtin_amdgcn_cvt_pk_fp8_f32(a, b, 0, false);
  int hi = __builtin_amdgcn_cvt_pk_fp8_f32(c, d, 0, false);
  return (uint32_t)(lo & 0xffff) | ((uint32_t)hi << 16);
}

// async global->LDS, 16B per lane; LDS dest is wave-uniform base + lane*16
__device__ __forceinline__ void gload_lds16(const void* g, void* l){
  __builtin_amdgcn_global_load_lds(
      (const __attribute__((address_space(1))) uint32_t*)g,
      (__attribute__((address_space(3))) uint32_t*)l, 16, 0, 0);
}

// ------------------------------------------- fused norm + transpose/convert ----
// One block per (nt, mat): reads the 64n x 384c f32 tile ONCE, writes V bf16
// inline, computes row norms from registers+LDS partials, then emits
// Q/K fp8 [n][c] from the bf16 LDS tile.
__global__ void prep_kernel(const float* __restrict__ feats,
                            const float* __restrict__ refs,
                            unsigned char* __restrict__ Qb,
                            unsigned char* __restrict__ Kb,
                            unsigned short* __restrict__ Vb){
  int nt = blockIdx.x, mat = blockIdx.y;
  __shared__ unsigned short tile[64][386];   // [n][c] bf16; 772B rows (odd dwords)
  __shared__ float ssp[64][17];              // per-n partial sums (16 producers)
  __shared__ float inv_sh[64];
  int t = threadIdx.x;
  bool isref = (mat >= B_);
  const float* src = isref ? refs  + (size_t)(mat - B_) * C_ * N_
                           : feats + (size_t)mat * C_ * N_;
  int n4  = t & 15;        // owns n = n4*4 .. +3 (fixed per thread)
  int crb = t >> 4;        // c-row base 0..15
  float ss4[4] = {0.f, 0.f, 0.f, 0.f};
#pragma unroll
  for (int ct = 0; ct < 6; ++ct){
#pragma unroll
    for (int i = 0; i < 4; ++i){
      int c = ct * 64 + crb + 16 * i;
      size_t off = (size_t)c * N_ + nt * 64 + n4 * 4;
      float4 v = *(const float4*)(src + off);
      ushort4 o;
      o.x = f2bf(v.x); o.y = f2bf(v.y); o.z = f2bf(v.z); o.w = f2bf(v.w);
      if (isref){
        unsigned short* vdst = Vb + (size_t)(mat - B_) * C_ * N_;
        *(ushort4*)(vdst + off) = o;       // V = raw bf16, same [c][n] layout
      }
      tile[n4*4+0][c] = o.x;
      tile[n4*4+1][c] = o.y;
      tile[n4*4+2][c] = o.z;
      tile[n4*4+3][c] = o.w;
      ss4[0] += v.x * v.x;  ss4[1] += v.y * v.y;
      ss4[2] += v.z * v.z;  ss4[3] += v.w * v.w;
    }
  }
#pragma unroll
  for (int j = 0; j < 4; ++j) ssp[n4*4+j][crb] = ss4[j];
  __syncthreads();
  if (t < 64){
    float s = 0.f;
#pragma unroll
    for (int p = 0; p < 16; ++p) s += ssp[t][p];
    inv_sh[t] = 1.f / fmaxf(sqrtf(s), 1e-12f);
  }
  __syncthreads();
  unsigned char* dst = isref ? Kb + (size_t)(mat - B_) * N_ * C_
                             : Qb + (size_t)mat * N_ * C_;
#pragma unroll
  for (int i = 0; i < 4; ++i){
    int nr = (t >> 4) + 16 * i;
    float iv = inv_sh[nr];
    unsigned char* drow = dst + (size_t)(nt * 64 + nr) * C_;
#pragma unroll
    for (int ct = 0; ct < 6; ++ct){
      int c0 = ct * 64 + (t & 15) * 4;
      uint32_t a0 = *(const uint32_t*)(&tile[nr][c0]);      // bf16 pair c0,c0+1
      uint32_t a1 = *(const uint32_t*)(&tile[nr][c0 + 2]);  // bf16 pair c0+2,+3
      uint32_t pk = pk_fp8x4(bf2f((unsigned short)(a0 & 0xffff)) * iv,
                             bf2f((unsigned short)(a0 >> 16))    * iv,
                             bf2f((unsigned short)(a1 & 0xffff)) * iv,
                             bf2f((unsigned short)(a1 >> 16))    * iv);
      *(uint32_t*)(drow + c0) = pk;
    }
  }
}

// ------------------------------------------------------------------ mask ----
__global__ void mask_kernel(const float* __restrict__ sopm,
                            float* __restrict__ maskp){
  int gid = blockIdx.x * 256 + threadIdx.x;       // 12800
  int b = gid / N_, n = gid - b * N_;
  int oy = n / HW_, ox = n - oy * HW_;
  const float* sp = sopm + (size_t)b * S_ * S_;
  float cy = oy * 4 + 1.5f, cx = ox * 4 + 1.5f;
  int y0 = 4*oy - 2; if (y0 < 0) y0 = 0;
  int y1 = 4*oy + 5; if (y1 > S_-1) y1 = S_-1;
  int x0 = 4*ox - 2; if (x0 < 0) x0 = 0;
  int x1 = 4*ox + 5; if (x1 > S_-1) x1 = S_-1;
  float wsy = 0.f, wsx = 0.f;
  for (int j = y0; j <= y1; ++j) wsy += 1.f - fabsf(j - cy) * 0.25f;
  for (int j = x0; j <= x1; ++j) wsx += 1.f - fabsf(j - cx) * 0.25f;
  float acc = 0.f;
  for (int jy = y0; jy <= y1; ++jy){
    float wy = 1.f - fabsf(jy - cy) * 0.25f;
    float rs = 0.f;
    for (int jx = x0; jx <= x1; ++jx)
      rs += (1.f - fabsf(jx - cx) * 0.25f) * sp[jy * S_ + jx];
    acc += wy * rs;
  }
  float val = acc / (wsy * wsx);
  maskp[gid] = (val > 0.3f) ? 1.f : 0.f;
}

// ------------------------------------------------------------- attention ----
// Full T15 pipeline: ONE barrier + one drain per iteration. K/V/P all
// double-buffered (LDS 81920 = 2x12K K + 2x24K V + 2x4K P -> 2 blocks/CU).
// grid 800 = (r*B+b)*25 + qtile (XCD-swizzled). Block: 4 waves.
// QK 2x2 wave-split; P block-shared; PV c-split (c=w*96..+96).
// Per iter t (cur = t&1); at entry: P(t) in pb[cur], K(t+1) in kb[cur^1],
// V(t) in vb[cur]:
//   stageV(t+1)->vb[cur^1]; stageK(t+2)->kb[cur]; pa-read(pb[cur]);
//   QK(t+1) [24 MFMA] ; PV(t) [24 MFMA] ; softmax(t+1) VALU overlaps the
//   MFMA drain; P-write(t+1)->pb[cur^1]; lgkm0+vmcnt0; bar.
// Safety: every buffer's writer is separated from its last reader by the
// single barrier (readers in iter t-1 finish at bar(t-1)).
#define KB0_   0
#define KB1_   12288
#define VB0_   24576
#define VB1_   49152
#define PB0_   73728
#define PB1_   77824
#define LDS_SZ 81920

__global__ __launch_bounds__(256, 2) void attn_kernel(
    const unsigned char* __restrict__ Qb,
    const unsigned char* __restrict__ Kb,
    const unsigned short* __restrict__ Vb,
    const float* __restrict__ log_tau,
    unsigned short* __restrict__ Or)
{
  __shared__ __align__(16) char lds[LDS_SZ];
  int wg   = blockIdx.x;
  int orig = (wg & 7) * 100 + (wg >> 3);   // XCD-contiguous chunks (800 = 8*100)
  int qt   = orig % 25;
  int rb   = orig / 25;                    // r*B + b
  int b    = rb & 7;
  int tid  = threadIdx.x;
  int lane = tid & 63;
  int w    = tid >> 6;
  int mw   = w >> 1;                       // m-half for QK
  int qw   = w & 1;                        // q-half for QK
  int l15  = lane & 15;
  int lg   = lane >> 4;

  float tau = expf(log_tau[0]);
  tau = fminf(fmaxf(tau, 0.005f), 0.1f);
  float sc = 1.4426950408889634f / tau;    // log2(e)/tau

  // Q fp8 fragments: 32 q rows (2 q-tiles) in regs (48 VGPR)
  i64t qreg[2][12];
#pragma unroll
  for (int qt2 = 0; qt2 < 2; ++qt2){
    const unsigned char* qp = Qb +
        ((size_t)b * N_ + qt * 64 + qw * 32 + qt2 * 16 + l15) * C_ + lg * 8;
#pragma unroll
    for (int ks = 0; ks < 12; ++ks)
      qreg[qt2][ks] = *(const i64t*)(qp + ks * 32);
  }

  // O accumulator: [qf2 0..3][cf 0..5] -> O[qf2*16 + lg*4 + rg][w*96 + cf*16 + l15]
  f32x4 o[4][6];
#pragma unroll
  for (int i = 0; i < 4; ++i)
#pragma unroll
    for (int j = 0; j < 6; ++j) o[i][j] = (f32x4){0.f,0.f,0.f,0.f};
  float lsum0 = 0.f, lsum1 = 0.f;          // l for q = qw*32 + {l15, 16+l15}

  const unsigned char*  kmat = Kb + (size_t)rb * N_ * C_;
  const unsigned short* vmat = Vb + (size_t)rb * C_ * N_;

  // per-lane global byte offsets for the 3 K gload_lds per wave
  int koffB[3];
#pragma unroll
  for (int i = 0; i < 3; ++i){
    int L = (w * 3 + i) * 64 + lane;              // granule 0..767
    int m   = L / 24;
    int pos = L - m * 24;
    int cc  = (pos >> 3) * 8 + ((pos & 7) ^ (m & 7));
    koffB[i] = m * C_ + cc * 16;
  }
  // per-lane global element offsets for the 6 V gload_lds per wave
  int voff[6];
#pragma unroll
  for (int i = 0; i < 6; ++i){
    int chunk = (w * 6 + i) * 64 + lane;          // 0..1535
    int line = chunk >> 3;
    int u    = (chunk & 7) ^ (line & 7);
    voff[i]  = (line * 2 + (u >> 2)) * N_ + (u & 3) * 8;
  }

  // P offsets: row q (64B), phys granule = logical ^ s(q), s(q) = (l15>>1)&3
  const int s_l  = (l15 >> 1) & 3;
  const int p_w0 = (qw*32      + l15) * 64 + (((2*mw + (lg >> 1)) ^ s_l) << 4) + (lg & 1) * 8;
  const int p_w1 = (qw*32 + 16 + l15) * 64 + (((2*mw + (lg >> 1)) ^ s_l) << 4) + (lg & 1) * 8;
  const int p_rc = ((lg ^ s_l) << 4) + l15 * 64;   // + qf2*1024

  auto stageK = [&](int t, int buf){
    const unsigned char* kb = kmat + (size_t)t * 32 * C_;
    char* kdst = lds + (buf ? KB1_ : KB0_) + w * 3072;
#pragma unroll
    for (int i = 0; i < 3; ++i) gload_lds16(kb + koffB[i], kdst + i * 1024);
  };
  auto stageV = [&](int t, int buf){
    const unsigned short* vb = vmat + t * 32;
    char* vdst = lds + (buf ? VB1_ : VB0_) + w * 6144;
#pragma unroll
    for (int i = 0; i < 6; ++i) gload_lds16(vb + voff[i], vdst + i * 1024);
  };
  const int krow = (mw * 16 + l15);        // K LDS row this lane reads
  auto computeQK = [&](const char* kbR, f32x4& a0acc, f32x4& a1acc){
#pragma unroll
    for (int ks = 0; ks < 12; ++ks){
      int lc  = 2 * ks + (lg >> 1);
      int off = ((lc >> 3) * 8 + ((lc & 7) ^ (krow & 7))) * 16 + (lg & 1) * 8;
      i64t a = *(const i64t*)(kbR + krow * 384 + off);
      a0acc = __builtin_amdgcn_mfma_f32_16x16x32_fp8_fp8(a, qreg[0][ks], a0acc, 0, 0, 0);
      a1acc = __builtin_amdgcn_mfma_f32_16x16x32_fp8_fp8(a, qreg[1][ks], a1acc, 0, 0, 0);
    }
  };

  // prologue: K0+V0 staged+drained; K1 issued; QK(0); softmax(0); P(0)->pb0
  stageK(0, 0);
  stageV(0, 0);
  asm volatile("s_waitcnt vmcnt(0)" ::: "memory");
  __builtin_amdgcn_sched_barrier(0);
  __builtin_amdgcn_s_barrier();
  __builtin_amdgcn_sched_barrier(0);
  stageK(1, 1);
  {
    f32x4 s0 = {0.f,0.f,0.f,0.f}, s1 = {0.f,0.f,0.f,0.f};
    computeQK(lds + KB0_, s0, s1);         // QK(0)
    ushort4 pw0, pw1;
    __bf16 h;
    float l0 = 0.f, l1 = 0.f;
    h = (__bf16)exp2f((s0[0]-1.f)*sc); l0 += (float)h; pw0.x = __builtin_bit_cast(unsigned short, h);
    h = (__bf16)exp2f((s0[1]-1.f)*sc); l0 += (float)h; pw0.y = __builtin_bit_cast(unsigned short, h);
    h = (__bf16)exp2f((s0[2]-1.f)*sc); l0 += (float)h; pw0.z = __builtin_bit_cast(unsigned short, h);
    h = (__bf16)exp2f((s0[3]-1.f)*sc); l0 += (float)h; pw0.w = __builtin_bit_cast(unsigned short, h);
    h = (__bf16)exp2f((s1[0]-1.f)*sc); l1 += (float)h; pw1.x = __builtin_bit_cast(unsigned short, h);
    h = (__bf16)exp2f((s1[1]-1.f)*sc); l1 += (float)h; pw1.y = __builtin_bit_cast(unsigned short, h);
    h = (__bf16)exp2f((s1[2]-1.f)*sc); l1 += (float)h; pw1.z = __builtin_bit_cast(unsigned short, h);
    h = (__bf16)exp2f((s1[3]-1.f)*sc); l1 += (float)h; pw1.w = __builtin_bit_cast(unsigned short, h);
    lsum0 += l0; lsum1 += l1;
    *(ushort4*)(lds + PB0_ + p_w0) = pw0;
    *(ushort4*)(lds + PB0_ + p_w1) = pw1;
  }
  asm volatile("s_waitcnt lgkmcnt(0) vmcnt(0)" ::: "memory");
  __builtin_amdgcn_sched_barrier(0);
  __builtin_amdgcn_s_barrier();            // P(0) visible; K(1) in LDS
  __builtin_amdgcn_sched_barrier(0);

  for (int mt = 0; mt < 50; ++mt){
    int cur = mt & 1;

    // ---- issue next-tile stages (full-phase flight before the end drain)
    if (mt + 1 < 50) stageV(mt + 1, cur ^ 1);
    if (mt + 2 < 50) stageK(mt + 2, cur);
    __builtin_amdgcn_sched_barrier(0);

    // ---- pa-read(mt) from pb[cur]
    bf16x8 pa[4];
    const char* pbR = lds + (cur ? PB1_ : PB0_);
#pragma unroll
    for (int qf2 = 0; qf2 < 4; ++qf2)
      pa[qf2] = *(const bf16x8*)(pbR + qf2 * 1024 + p_rc);

    // ---- MFMA burst: QK(mt+1) + PV(mt); softmax(mt+1) VALU overlaps drain
    f32x4 s0 = {0.f,0.f,0.f,0.f}, s1 = {0.f,0.f,0.f,0.f};
    __builtin_amdgcn_s_setprio(1);
    if (mt + 1 < 50)
      computeQK(lds + ((cur ^ 1) ? KB1_ : KB0_), s0, s1);  // QK(mt+1)
    const char* vbR = lds + (cur ? VB1_ : VB0_);
#pragma unroll
    for (int cf = 0; cf < 6; ++cf){
      int c  = w * 96 + cf * 16 + l15;
      int vo = (c >> 1) * 128 + (((lg | ((c & 1) << 2)) ^ ((c >> 1) & 7)) << 4);
      bf16x8 vf = *(const bf16x8*)(vbR + vo);
#pragma unroll
      for (int qf2 = 0; qf2 < 4; ++qf2)
        o[qf2][cf] = __builtin_amdgcn_mfma_f32_16x16x32_bf16(pa[qf2], vf, o[qf2][cf], 0, 0, 0);
    }
    __builtin_amdgcn_s_setprio(0);

    // ---- softmax(mt+1) -> P-write into pb[cur^1]
    if (mt + 1 < 50){
      ushort4 pw0, pw1;
      __bf16 h;
      float l0 = 0.f, l1 = 0.f;
      h = (__bf16)exp2f((s0[0]-1.f)*sc); l0 += (float)h; pw0.x = __builtin_bit_cast(unsigned short, h);
      h = (__bf16)exp2f((s0[1]-1.f)*sc); l0 += (float)h; pw0.y = __builtin_bit_cast(unsigned short, h);
      h = (__bf16)exp2f((s0[2]-1.f)*sc); l0 += (float)h; pw0.z = __builtin_bit_cast(unsigned short, h);
      h = (__bf16)exp2f((s0[3]-1.f)*sc); l0 += (float)h; pw0.w = __builtin_bit_cast(unsigned short, h);
      h = (__bf16)exp2f((s1[0]-1.f)*sc); l1 += (float)h; pw1.x = __builtin_bit_cast(unsigned short, h);
      h = (__bf16)exp2f((s1[1]-1.f)*sc); l1 += (float)h; pw1.y = __builtin_bit_cast(unsigned short, h);
      h = (__bf16)exp2f((s1[2]-1.f)*sc); l1 += (float)h; pw1.z = __builtin_bit_cast(unsigned short, h);
      h = (__bf16)exp2f((s1[3]-1.f)*sc); l1 += (float)h; pw1.w = __builtin_bit_cast(unsigned short, h);
      lsum0 += l0; lsum1 += l1;
      char* pbW = lds + ((cur ^ 1) ? PB1_ : PB0_);
      *(ushort4*)(pbW + p_w0) = pw0;
      *(ushort4*)(pbW + p_w1) = pw1;
    }

    // ---- single drain + single barrier per iteration
    asm volatile("s_waitcnt lgkmcnt(0) vmcnt(0)" ::: "memory");
    __builtin_amdgcn_sched_barrier(0);
    __builtin_amdgcn_s_barrier();   // P(t+1) visible; K(t+2), V(t+1) in LDS;
    __builtin_amdgcn_sched_barrier(0); // all reads of pb/kb/vb[cur] retired
  }

  // ---- finalize: l per q = sum over both m-half waves
  lsum0 += __shfl_xor(lsum0, 16, 64);
  lsum0 += __shfl_xor(lsum0, 32, 64);
  lsum1 += __shfl_xor(lsum1, 16, 64);
  lsum1 += __shfl_xor(lsum1, 32, 64);
  __syncthreads();                         // loop done; LDS reusable
  float* lsh = (float*)lds;                // [2 mw][64 q]
  if (lg == 0){
    lsh[mw * 64 + qw * 32 + l15]      = lsum0;
    lsh[mw * 64 + qw * 32 + 16 + l15] = lsum1;
  }
  __syncthreads();
  float invl[4][4];
#pragma unroll
  for (int qf2 = 0; qf2 < 4; ++qf2)
#pragma unroll
    for (int rg = 0; rg < 4; ++rg){
      int q = qf2 * 16 + lg * 4 + rg;
      invl[qf2][rg] = 1.f / (lsh[q] + lsh[64 + q]);
    }

  int qbase = qt * 64;
  unsigned short* op = Or + ((size_t)rb * N_ + qbase) * C_ + w * 96 + l15;
#pragma unroll
  for (int qf2 = 0; qf2 < 4; ++qf2){
#pragma unroll
    for (int cf = 0; cf < 6; ++cf){
#pragma unroll
      for (int rg = 0; rg < 4; ++rg){
        int q = qf2 * 16 + lg * 4 + rg;
        op[(size_t)q * C_ + cf * 16] = f2bf(o[qf2][cf][rg] * invl[qf2][rg]);
      }
    }
  }
}

// --------------------------------------------------------------- combine ----
// out[b][c][n] = feats + mask*alpha*(sum_r Or/4 - feats); transpose [n][c]->[c][n]
__global__ void combine_kernel(const unsigned short* __restrict__ Or,
                               const float* __restrict__ feats,
                               const float* __restrict__ maskp,
                               const float* __restrict__ alpha_raw,
                               float* __restrict__ out){
  int nt = blockIdx.x, ct = blockIdx.y, b = blockIdx.z;
  __shared__ float tile[64][65];
  float alpha = 1.f / (1.f + expf(-alpha_raw[0]));
  int t = threadIdx.x;
#pragma unroll
  for (int i = 0; i < 4; ++i){
    int chunk = t + 256 * i;
    int nr = chunk >> 4, c4 = chunk & 15;
    size_t base = ((size_t)b * N_ + nt * 64 + nr) * C_ + ct * 64 + c4 * 4;
    float4 s = {0.f,0.f,0.f,0.f};
#pragma unroll
    for (int r = 0; r < 4; ++r){
      ushort4 v = *(const ushort4*)(Or + (size_t)r * B_ * N_ * C_ + base);
      s.x += bf2f(v.x); s.y += bf2f(v.y); s.z += bf2f(v.z); s.w += bf2f(v.w);
    }
    tile[nr][c4*4+0] = s.x; tile[nr][c4*4+1] = s.y;
    tile[nr][c4*4+2] = s.z; tile[nr][c4*4+3] = s.w;
  }
  __syncthreads();
#pragma unroll
  for (int i = 0; i < 4; ++i){
    int chunk = t + 256 * i;
    int cr = chunk >> 4, n4 = chunk & 15;
    size_t fb = ((size_t)b * C_ + ct * 64 + cr) * N_ + nt * 64 + n4 * 4;
    float4 f  = *(const float4*)(feats + fb);
    float4 mk = *(const float4*)(maskp + (size_t)b * N_ + nt * 64 + n4 * 4);
    float4 ov;
    ov.x = f.x + mk.x * alpha * (tile[n4*4+0][cr] * 0.25f - f.x);
    ov.y = f.y + mk.y * alpha * (tile[n4*4+1][cr] * 0.25f - f.y);
    ov.z = f.z + mk.z * alpha * (tile[n4*4+2][cr] * 0.25f - f.z);
    ov.w = f.w + mk.w * alpha * (tile[n4*4+3][cr] * 0.25f - f.w);
    *(float4*)(out + fb) = ov;
  }
}

// ws-too-small sentinel: recognizable absmax ~1e6
__global__ void poison_kernel(float* out, int n){
  int i = blockIdx.x * 256 + threadIdx.x;
  if (i < n) out[i] = 1.0e6f;
}

extern "C" void kernel_launch(void* const* d_in, const int* in_sizes, int n_in,
                              void* d_out, int out_size, void* d_ws, size_t ws_size,
                              hipStream_t stream){
  const float* feats     = (const float*)d_in[0];
  const float* refs      = (const float*)d_in[1];
  const float* sopm      = (const float*)d_in[2];
  const float* log_tau   = (const float*)d_in[3];
  const float* alpha_raw = (const float*)d_in[4];
  float* out = (float*)d_out;

  const size_t SZ_MASK = (size_t)B_ * N_ * 4;              //    51,200
  const size_t SZ_QB   = (size_t)B_ * N_ * C_;             // 4,915,200 (fp8)
  const size_t SZ_KB   = (size_t)R_ * B_ * N_ * C_;        // 19,660,800 (fp8)
  const size_t SZ_VB   = (size_t)R_ * B_ * N_ * C_ * 2;    // 39,321,600 (bf16)
  const size_t SZ_OR   = (size_t)R_ * B_ * N_ * C_ * 2;    // 39,321,600 (bf16)
  const size_t need = SZ_MASK + SZ_QB + SZ_KB + SZ_VB + SZ_OR;

  if (ws_size < need){
    poison_kernel<<<(out_size + 255) / 256, 256, 0, stream>>>(out, out_size);
    return;
  }
  char* ws = (char*)d_ws;
  float*          maskp = (float*)ws;
  unsigned char*  Qb    = (unsigned char*)(ws + SZ_MASK);
  unsigned char*  Kb    = (unsigned char*)(ws + SZ_MASK + SZ_QB);
  unsigned short* Vb    = (unsigned short*)(ws + SZ_MASK + SZ_QB + SZ_KB);
  unsigned short* Or    = (unsigned short*)(ws + SZ_MASK + SZ_QB + SZ_KB + SZ_VB);

  mask_kernel   <<<50, 256, 0, stream>>>(sopm, maskp);
  prep_kernel   <<<dim3(25, 40), 256, 0, stream>>>(feats, refs, Qb, Kb, Vb);
  attn_kernel   <<<800, 256, 0, stream>>>(Qb, Kb, Vb, log_tau, Or);
  combine_kernel<<<dim3(25, 6, 8), 256, 0, stream>>>(Or, feats, maskp, alpha_raw, out);
}